// Round 1
// baseline (2043.959 us; speedup 1.0000x reference)
//
#include <hip/hip_runtime.h>

#define N_NODES 100000
#define N_EDGES 500000
#define DIM 128

__global__ __launch_bounds__(256) void count_kernel(const int* __restrict__ dst,
                                                    float* __restrict__ cnt, int n) {
    int e = blockIdx.x * 256 + threadIdx.x;
    if (e < n) atomicAdd(&cnt[dst[e]], 1.0f);
}

__global__ __launch_bounds__(256) void rinv_kernel(float* __restrict__ cnt, int n) {
    int i = blockIdx.x * 256 + threadIdx.x;
    if (i < n) cnt[i] = 1.0f / fmaxf(cnt[i], 1.0f);
}

// Scatter-add of 128-dim source features over edges. One thread = 4 feats of one edge.
__global__ __launch_bounds__(256) void seg_sum_kernel(const float* __restrict__ x,
                                                      const int* __restrict__ src,
                                                      const int* __restrict__ dst,
                                                      float* __restrict__ sum) {
    int idx = blockIdx.x * 256 + threadIdx.x;
    int e = idx >> 5;
    if (e >= N_EDGES) return;
    int f = (idx & 31) << 2;
    int s = src[e], d = dst[e];
    float4 v = *reinterpret_cast<const float4*>(&x[s * DIM + f]);
    float* o = &sum[d * DIM + f];
    atomicAdd(o + 0, v.x);
    atomicAdd(o + 1, v.y);
    atomicAdd(o + 2, v.z);
    atomicAdd(o + 3, v.w);
}

// Scalar segment-sum (layer 2, after linearity swap: seg_mean(h)@w = seg_mean(h@w)).
__global__ __launch_bounds__(256) void scalar_seg_kernel(const float* __restrict__ sval,
                                                         const int* __restrict__ src,
                                                         const int* __restrict__ dst,
                                                         float* __restrict__ ssum) {
    int e = blockIdx.x * 256 + threadIdx.x;
    if (e < N_EDGES) atomicAdd(&ssum[dst[e]], sval[src[e]]);
}

// h = relu(Xs@Ws.T + bs + (nsum*rinv)@Wn.T + bn); fused epilogue computes
// dself[i] = h[i]·w2a and dcross[i] = h[i]·w2b (layer-2 dots) — h never stored.
// Tile: 64 rows x 128 cols, 256 threads, 4x8 micro-tile per thread, K=256.
__global__ __launch_bounds__(256) void gemm_l1_kernel(
    const float* __restrict__ Xs, const float* __restrict__ nsum,
    const float* __restrict__ rinv,
    const float* __restrict__ Ws, const float* __restrict__ Wn,
    const float* __restrict__ bs, const float* __restrict__ bn,
    const float* __restrict__ w2a, const float* __restrict__ w2b,
    float* __restrict__ dself, float* __restrict__ dcross) {
    __shared__ float Asub[32][68];   // [k][row], padded: 4-way worst on write, clean f4 read
    __shared__ float Bsub[32][132];  // [k][col], padded
    const int tid = threadIdx.x;
    const int tc = tid & 15;   // column group: cols tc*8 .. tc*8+7
    const int tr = tid >> 4;   // row group:    rows tr*4 .. tr*4+3
    const int row0 = blockIdx.x * 64;

    float acc[4][8];
#pragma unroll
    for (int i = 0; i < 4; ++i)
#pragma unroll
        for (int j = 0; j < 8; ++j) acc[i][j] = 0.f;

    for (int kb = 0; kb < 256; kb += 32) {
        const bool self = (kb < 128);
        const int kg = self ? kb : kb - 128;
        // ---- stage A chunk: 64 rows x 32 k ----
        {
            const int r = tid >> 3;
            const int kk = (tid & 7) << 2;
#pragma unroll
            for (int p = 0; p < 2; ++p) {
                int rr = p * 32 + r;
                int grow = row0 + rr;
                float4 v = make_float4(0.f, 0.f, 0.f, 0.f);
                if (grow < N_NODES) {
                    if (self) {
                        v = *reinterpret_cast<const float4*>(&Xs[grow * DIM + kg + kk]);
                    } else {
                        v = *reinterpret_cast<const float4*>(&nsum[grow * DIM + kg + kk]);
                        float sc = rinv[grow];
                        v.x *= sc; v.y *= sc; v.z *= sc; v.w *= sc;
                    }
                }
                Asub[kk + 0][rr] = v.x;
                Asub[kk + 1][rr] = v.y;
                Asub[kk + 2][rr] = v.z;
                Asub[kk + 3][rr] = v.w;
            }
        }
        // ---- stage B chunk: 128 cols x 32 k (transposed into [k][col]) ----
        {
            const int kk = (tid & 7) << 2;
            const float* W = self ? Ws : Wn;
#pragma unroll
            for (int p = 0; p < 4; ++p) {
                int c = p * 32 + (tid >> 3);
                float4 v = *reinterpret_cast<const float4*>(&W[c * DIM + kg + kk]);
                Bsub[kk + 0][c] = v.x;
                Bsub[kk + 1][c] = v.y;
                Bsub[kk + 2][c] = v.z;
                Bsub[kk + 3][c] = v.w;
            }
        }
        __syncthreads();
#pragma unroll
        for (int kk = 0; kk < 32; ++kk) {
            float a[4], b[8];
            *reinterpret_cast<float4*>(&a[0]) =
                *reinterpret_cast<const float4*>(&Asub[kk][tr * 4]);
            *reinterpret_cast<float4*>(&b[0]) =
                *reinterpret_cast<const float4*>(&Bsub[kk][tc * 8]);
            *reinterpret_cast<float4*>(&b[4]) =
                *reinterpret_cast<const float4*>(&Bsub[kk][tc * 8 + 4]);
#pragma unroll
            for (int i = 0; i < 4; ++i)
#pragma unroll
                for (int j = 0; j < 8; ++j) acc[i][j] = fmaf(a[i], b[j], acc[i][j]);
        }
        __syncthreads();
    }

    // ---- epilogue: bias + relu + two layer-2 dot products, 16-lane shuffle reduce ----
    float bias[8], wa[8], wb[8];
#pragma unroll
    for (int j = 0; j < 8; ++j) {
        int c = tc * 8 + j;
        bias[j] = bs[c] + bn[c];
        wa[j] = w2a[c];
        wb[j] = w2b[c];
    }
#pragma unroll
    for (int i = 0; i < 4; ++i) {
        float pa = 0.f, pb = 0.f;
#pragma unroll
        for (int j = 0; j < 8; ++j) {
            float h = fmaxf(acc[i][j] + bias[j], 0.f);
            pa = fmaf(h, wa[j], pa);
            pb = fmaf(h, wb[j], pb);
        }
#pragma unroll
        for (int m = 1; m < 16; m <<= 1) {
            pa += __shfl_xor(pa, m);
            pb += __shfl_xor(pb, m);
        }
        int grow = row0 + tr * 4 + i;
        if (tc == 0 && grow < N_NODES) {
            dself[grow] = pa;
            dcross[grow] = pb;
        }
    }
}

__global__ __launch_bounds__(256) void finalize_kernel(
    const float* __restrict__ dself_u, const float* __restrict__ ssum_u,
    const float* __restrict__ rinv_pb, const float* __restrict__ b2bs,
    const float* __restrict__ b2bn, const float* __restrict__ dself_t,
    const float* __restrict__ ssum_t, const float* __restrict__ rinv_posts,
    const float* __restrict__ b2ps, const float* __restrict__ b2pn,
    float* __restrict__ out) {
    int i = blockIdx.x * 256 + threadIdx.x;
    if (i >= N_NODES) return;
    out[i] = dself_u[i] + ssum_u[i] * rinv_pb[i] + b2bs[0] + b2bn[0];
    out[N_NODES + i] = dself_t[i] + ssum_t[i] * rinv_posts[i] + b2ps[0] + b2pn[0];
}

extern "C" void kernel_launch(void* const* d_in, const int* in_sizes, int n_in,
                              void* d_out, int out_size, void* d_ws, size_t ws_size,
                              hipStream_t stream) {
    const float* x_user  = (const float*)d_in[0];
    const float* x_tweet = (const float*)d_in[1];
    const float* w1ps = (const float*)d_in[2];  const float* b1ps = (const float*)d_in[3];
    const float* w1pn = (const float*)d_in[4];  const float* b1pn = (const float*)d_in[5];
    const float* w1bs = (const float*)d_in[6];  const float* b1bs = (const float*)d_in[7];
    const float* w1bn = (const float*)d_in[8];  const float* b1bn = (const float*)d_in[9];
    const float* w2ps = (const float*)d_in[10]; const float* b2ps = (const float*)d_in[11];
    const float* w2pn = (const float*)d_in[12]; const float* b2pn = (const float*)d_in[13];
    const float* w2bs = (const float*)d_in[14]; const float* b2bs = (const float*)d_in[15];
    const float* w2bn = (const float*)d_in[16]; const float* b2bn = (const float*)d_in[17];
    const int* src_posts = (const int*)d_in[18];
    const int* dst_posts = (const int*)d_in[19];
    const int* src_pb    = (const int*)d_in[20];
    const int* dst_pb    = (const int*)d_in[21];
    float* out = (float*)d_out;

    float* ws = (float*)d_ws;
    float* neigh      = ws;                                  // N*128
    float* rinv_posts = neigh + (size_t)N_NODES * DIM;       // N
    float* rinv_pb    = rinv_posts + N_NODES;                // N
    float* dself_t    = rinv_pb + N_NODES;                   // N
    float* scross_t   = dself_t + N_NODES;                   // N (h_tweet · w2bn)
    float* dself_u    = scross_t + N_NODES;                  // N
    float* scross_u   = dself_u + N_NODES;                   // N (h_user · w2pn)
    float* ssum_t     = scross_u + N_NODES;                  // N
    float* ssum_u     = ssum_t + N_NODES;                    // N

    const int gE  = (N_EDGES + 255) / 256;
    const int gN  = (N_NODES + 255) / 256;
    const int gSS = (N_EDGES * 32 + 255) / 256;
    const int gG  = (N_NODES + 63) / 64;

    // in-degree counts -> reciprocals (shared by both layers, same edge lists)
    hipMemsetAsync(rinv_posts, 0, 2 * N_NODES * sizeof(float), stream);
    count_kernel<<<gE, 256, 0, stream>>>(dst_posts, rinv_posts, N_EDGES);
    count_kernel<<<gE, 256, 0, stream>>>(dst_pb, rinv_pb, N_EDGES);
    rinv_kernel<<<(2 * N_NODES + 255) / 256, 256, 0, stream>>>(rinv_posts, 2 * N_NODES);

    // relation 'posts': seg_mean(x_user) -> tweet side, then h_tweet GEMM (+L2 dots)
    hipMemsetAsync(neigh, 0, (size_t)N_NODES * DIM * sizeof(float), stream);
    seg_sum_kernel<<<gSS, 256, 0, stream>>>(x_user, src_posts, dst_posts, neigh);
    gemm_l1_kernel<<<gG, 256, 0, stream>>>(x_tweet, neigh, rinv_posts,
                                           w1ps, w1pn, b1ps, b1pn,
                                           w2ps, w2bn, dself_t, scross_t);

    // relation 'posted_by': seg_mean(x_tweet) -> user side, then h_user GEMM (+L2 dots)
    hipMemsetAsync(neigh, 0, (size_t)N_NODES * DIM * sizeof(float), stream);
    seg_sum_kernel<<<gSS, 256, 0, stream>>>(x_tweet, src_pb, dst_pb, neigh);
    gemm_l1_kernel<<<gG, 256, 0, stream>>>(x_user, neigh, rinv_pb,
                                           w1bs, w1bn, b1bs, b1bn,
                                           w2bs, w2pn, dself_u, scross_u);

    // layer-2 neighbor terms as scalar segment means (linearity of seg_mean + matmul)
    hipMemsetAsync(ssum_t, 0, 2 * N_NODES * sizeof(float), stream);
    scalar_seg_kernel<<<gE, 256, 0, stream>>>(scross_u, src_posts, dst_posts, ssum_t);
    scalar_seg_kernel<<<gE, 256, 0, stream>>>(scross_t, src_pb, dst_pb, ssum_u);

    finalize_kernel<<<gN, 256, 0, stream>>>(dself_u, ssum_u, rinv_pb, b2bs, b2bn,
                                            dself_t, ssum_t, rinv_posts, b2ps, b2pn, out);
}

// Round 2
// 426.298 us; speedup vs baseline: 4.7947x; 4.7947x over previous
//
#include <hip/hip_runtime.h>

#define N_NODES 100000
#define N_EDGES 500000
#define DIM 128
#define SCAN_BLOCKS ((N_NODES + 255) / 256)   // 391

// ---------------- CSR build ----------------

__global__ __launch_bounds__(256) void hist_kernel(const int* __restrict__ dst,
                                                   int* __restrict__ deg) {
    int e = blockIdx.x * 256 + threadIdx.x;
    if (e < N_EDGES) atomicAdd(&deg[dst[e]], 1);
}

__global__ __launch_bounds__(256) void scan_block_kernel(const int* __restrict__ deg,
                                                         int* __restrict__ excl,
                                                         int* __restrict__ bsums) {
    __shared__ int tmp[256];
    int t = threadIdx.x;
    int i = blockIdx.x * 256 + t;
    int v = (i < N_NODES) ? deg[i] : 0;
    tmp[t] = v;
    __syncthreads();
#pragma unroll
    for (int off = 1; off < 256; off <<= 1) {
        int x = (t >= off) ? tmp[t - off] : 0;
        __syncthreads();
        tmp[t] += x;
        __syncthreads();
    }
    if (i < N_NODES) excl[i] = tmp[t] - v;   // exclusive within block
    if (t == 255) bsums[blockIdx.x] = tmp[255];
}

__global__ __launch_bounds__(512) void scan_sums_kernel(int* __restrict__ bsums, int nb) {
    __shared__ int tmp[512];
    int t = threadIdx.x;
    int v = (t < nb) ? bsums[t] : 0;
    tmp[t] = v;
    __syncthreads();
#pragma unroll
    for (int off = 1; off < 512; off <<= 1) {
        int x = (t >= off) ? tmp[t - off] : 0;
        __syncthreads();
        tmp[t] += x;
        __syncthreads();
    }
    if (t < nb) bsums[t] = tmp[t] - v;       // exclusive block offsets
}

__global__ __launch_bounds__(256) void scan_add_kernel(int* __restrict__ excl,
                                                       const int* __restrict__ bsums) {
    int i = blockIdx.x * 256 + threadIdx.x;
    if (i < N_NODES) excl[i] += bsums[blockIdx.x];
}

__global__ __launch_bounds__(256) void scatter_kernel(const int* __restrict__ src,
                                                      const int* __restrict__ dst,
                                                      const int* __restrict__ rs,
                                                      int* __restrict__ cursor,
                                                      int* __restrict__ csr) {
    int e = blockIdx.x * 256 + threadIdx.x;
    if (e < N_EDGES) {
        int d = dst[e];
        int p = atomicAdd(&cursor[d], 1);
        csr[rs[d] + p] = src[e];
    }
}

// ---------------- segment means via CSR (no atomics) ----------------

// 32 lanes per dst node, each lane owns 4 contiguous feats (float4).
__global__ __launch_bounds__(256) void seg_mean_csr_kernel(const float* __restrict__ x,
                                                           const int* __restrict__ csr,
                                                           const int* __restrict__ rs,
                                                           float* __restrict__ out) {
    int idx = blockIdx.x * 256 + threadIdx.x;
    int node = idx >> 5;
    if (node >= N_NODES) return;
    int f = (idx & 31) << 2;
    int beg = rs[node];
    int end = (node == N_NODES - 1) ? N_EDGES : rs[node + 1];
    float4 acc = make_float4(0.f, 0.f, 0.f, 0.f);
    for (int e = beg; e < end; ++e) {
        int s = csr[e];  // broadcast across the 32 lanes (same address)
        float4 v = *reinterpret_cast<const float4*>(&x[s * DIM + f]);
        acc.x += v.x; acc.y += v.y; acc.z += v.z; acc.w += v.w;
    }
    float r = 1.0f / fmaxf((float)(end - beg), 1.0f);
    acc.x *= r; acc.y *= r; acc.z *= r; acc.w *= r;
    *reinterpret_cast<float4*>(&out[node * DIM + f]) = acc;
}

// Layer-2 scalar segment mean (linearity: seg_mean(h)@w2 = seg_mean(h@w2)).
__global__ __launch_bounds__(256) void scalar_seg_csr_kernel(const float* __restrict__ sval,
                                                             const int* __restrict__ csr,
                                                             const int* __restrict__ rs,
                                                             float* __restrict__ smean) {
    int node = blockIdx.x * 256 + threadIdx.x;
    if (node >= N_NODES) return;
    int beg = rs[node];
    int end = (node == N_NODES - 1) ? N_EDGES : rs[node + 1];
    float a = 0.f;
    for (int e = beg; e < end; ++e) a += sval[csr[e]];
    smean[node] = a / fmaxf((float)(end - beg), 1.0f);
}

// ---------------- fused layer-1 GEMM + layer-2 dots ----------------
// h = relu(Xs@Ws.T + bs + nmean@Wn.T + bn); epilogue: dself=h·w2a, dcross=h·w2b.
__global__ __launch_bounds__(256) void gemm_l1_kernel(
    const float* __restrict__ Xs, const float* __restrict__ nmean,
    const float* __restrict__ Ws, const float* __restrict__ Wn,
    const float* __restrict__ bs, const float* __restrict__ bn,
    const float* __restrict__ w2a, const float* __restrict__ w2b,
    float* __restrict__ dself, float* __restrict__ dcross) {
    __shared__ float Asub[32][68];
    __shared__ float Bsub[32][132];
    const int tid = threadIdx.x;
    const int tc = tid & 15;
    const int tr = tid >> 4;
    const int row0 = blockIdx.x * 64;

    float acc[4][8];
#pragma unroll
    for (int i = 0; i < 4; ++i)
#pragma unroll
        for (int j = 0; j < 8; ++j) acc[i][j] = 0.f;

    for (int kb = 0; kb < 256; kb += 32) {
        const bool self = (kb < 128);
        const int kg = kb & 127;
        {
            const float* P = self ? Xs : nmean;
            const int r = tid >> 3;
            const int kk = (tid & 7) << 2;
#pragma unroll
            for (int p = 0; p < 2; ++p) {
                int rr = p * 32 + r;
                int grow = row0 + rr;
                float4 v = make_float4(0.f, 0.f, 0.f, 0.f);
                if (grow < N_NODES)
                    v = *reinterpret_cast<const float4*>(&P[grow * DIM + kg + kk]);
                Asub[kk + 0][rr] = v.x;
                Asub[kk + 1][rr] = v.y;
                Asub[kk + 2][rr] = v.z;
                Asub[kk + 3][rr] = v.w;
            }
        }
        {
            const int kk = (tid & 7) << 2;
            const float* W = self ? Ws : Wn;
#pragma unroll
            for (int p = 0; p < 4; ++p) {
                int c = p * 32 + (tid >> 3);
                float4 v = *reinterpret_cast<const float4*>(&W[c * DIM + kg + kk]);
                Bsub[kk + 0][c] = v.x;
                Bsub[kk + 1][c] = v.y;
                Bsub[kk + 2][c] = v.z;
                Bsub[kk + 3][c] = v.w;
            }
        }
        __syncthreads();
#pragma unroll
        for (int kk = 0; kk < 32; ++kk) {
            float a[4], b[8];
            *reinterpret_cast<float4*>(&a[0]) =
                *reinterpret_cast<const float4*>(&Asub[kk][tr * 4]);
            *reinterpret_cast<float4*>(&b[0]) =
                *reinterpret_cast<const float4*>(&Bsub[kk][tc * 8]);
            *reinterpret_cast<float4*>(&b[4]) =
                *reinterpret_cast<const float4*>(&Bsub[kk][tc * 8 + 4]);
#pragma unroll
            for (int i = 0; i < 4; ++i)
#pragma unroll
                for (int j = 0; j < 8; ++j) acc[i][j] = fmaf(a[i], b[j], acc[i][j]);
        }
        __syncthreads();
    }

    float bias[8], wa[8], wb[8];
#pragma unroll
    for (int j = 0; j < 8; ++j) {
        int c = tc * 8 + j;
        bias[j] = bs[c] + bn[c];
        wa[j] = w2a[c];
        wb[j] = w2b[c];
    }
#pragma unroll
    for (int i = 0; i < 4; ++i) {
        float pa = 0.f, pb = 0.f;
#pragma unroll
        for (int j = 0; j < 8; ++j) {
            float h = fmaxf(acc[i][j] + bias[j], 0.f);
            pa = fmaf(h, wa[j], pa);
            pb = fmaf(h, wb[j], pb);
        }
#pragma unroll
        for (int m = 1; m < 16; m <<= 1) {
            pa += __shfl_xor(pa, m);
            pb += __shfl_xor(pb, m);
        }
        int grow = row0 + tr * 4 + i;
        if (tc == 0 && grow < N_NODES) {
            dself[grow] = pa;
            dcross[grow] = pb;
        }
    }
}

__global__ __launch_bounds__(256) void finalize_kernel(
    const float* __restrict__ dself_u, const float* __restrict__ smean_u,
    const float* __restrict__ b2bs, const float* __restrict__ b2bn,
    const float* __restrict__ dself_t, const float* __restrict__ smean_t,
    const float* __restrict__ b2ps, const float* __restrict__ b2pn,
    float* __restrict__ out) {
    int i = blockIdx.x * 256 + threadIdx.x;
    if (i >= N_NODES) return;
    out[i] = dself_u[i] + smean_u[i] + b2bs[0] + b2bn[0];
    out[N_NODES + i] = dself_t[i] + smean_t[i] + b2ps[0] + b2pn[0];
}

extern "C" void kernel_launch(void* const* d_in, const int* in_sizes, int n_in,
                              void* d_out, int out_size, void* d_ws, size_t ws_size,
                              hipStream_t stream) {
    const float* x_user  = (const float*)d_in[0];
    const float* x_tweet = (const float*)d_in[1];
    const float* w1ps = (const float*)d_in[2];  const float* b1ps = (const float*)d_in[3];
    const float* w1pn = (const float*)d_in[4];  const float* b1pn = (const float*)d_in[5];
    const float* w1bs = (const float*)d_in[6];  const float* b1bs = (const float*)d_in[7];
    const float* w1bn = (const float*)d_in[8];  const float* b1bn = (const float*)d_in[9];
    const float* w2ps = (const float*)d_in[10]; const float* b2ps = (const float*)d_in[11];
    const float* w2pn = (const float*)d_in[12]; const float* b2pn = (const float*)d_in[13];
    const float* w2bs = (const float*)d_in[14]; const float* b2bs = (const float*)d_in[15];
    const float* w2bn = (const float*)d_in[16]; const float* b2bn = (const float*)d_in[17];
    const int* src_posts = (const int*)d_in[18];
    const int* dst_posts = (const int*)d_in[19];
    const int* src_pb    = (const int*)d_in[20];
    const int* dst_pb    = (const int*)d_in[21];
    float* out = (float*)d_out;

    // workspace layout (4B elements, all regions 16B-aligned)
    char* wsb = (char*)d_ws;
    float* neigh    = (float*)wsb;                          wsb += (size_t)N_NODES * DIM * 4;
    int* csr_posts  = (int*)wsb;                            wsb += (size_t)N_EDGES * 4;
    int* csr_pb     = (int*)wsb;                            wsb += (size_t)N_EDGES * 4;
    int* rs_posts   = (int*)wsb;                            wsb += (size_t)(N_NODES + 4) * 4;
    int* rs_pb      = (int*)wsb;                            wsb += (size_t)(N_NODES + 4) * 4;
    int* deg        = (int*)wsb;                            wsb += (size_t)N_NODES * 4;   // also cursor
    int* bsums      = (int*)wsb;                            wsb += 512 * 4;
    float* dself_t  = (float*)wsb;                          wsb += (size_t)N_NODES * 4;
    float* scross_t = (float*)wsb;                          wsb += (size_t)N_NODES * 4;
    float* dself_u  = (float*)wsb;                          wsb += (size_t)N_NODES * 4;
    float* scross_u = (float*)wsb;                          wsb += (size_t)N_NODES * 4;
    float* smean_t  = (float*)wsb;                          wsb += (size_t)N_NODES * 4;
    float* smean_u  = (float*)wsb;                          wsb += (size_t)N_NODES * 4;

    const int gE = (N_EDGES + 255) / 256;
    const int gN = (N_NODES + 255) / 256;
    const int gSM = (N_NODES * 32 + 255) / 256;
    const int gG = (N_NODES + 63) / 64;

    // ---- build CSR for 'posts' (grouped by dst_posts) ----
    hipMemsetAsync(deg, 0, N_NODES * sizeof(int), stream);
    hist_kernel<<<gE, 256, 0, stream>>>(dst_posts, deg);
    scan_block_kernel<<<SCAN_BLOCKS, 256, 0, stream>>>(deg, rs_posts, bsums);
    scan_sums_kernel<<<1, 512, 0, stream>>>(bsums, SCAN_BLOCKS);
    scan_add_kernel<<<SCAN_BLOCKS, 256, 0, stream>>>(rs_posts, bsums);
    hipMemsetAsync(deg, 0, N_NODES * sizeof(int), stream);
    scatter_kernel<<<gE, 256, 0, stream>>>(src_posts, dst_posts, rs_posts, deg, csr_posts);

    // ---- build CSR for 'posted_by' ----
    hipMemsetAsync(deg, 0, N_NODES * sizeof(int), stream);
    hist_kernel<<<gE, 256, 0, stream>>>(dst_pb, deg);
    scan_block_kernel<<<SCAN_BLOCKS, 256, 0, stream>>>(deg, rs_pb, bsums);
    scan_sums_kernel<<<1, 512, 0, stream>>>(bsums, SCAN_BLOCKS);
    scan_add_kernel<<<SCAN_BLOCKS, 256, 0, stream>>>(rs_pb, bsums);
    hipMemsetAsync(deg, 0, N_NODES * sizeof(int), stream);
    scatter_kernel<<<gE, 256, 0, stream>>>(src_pb, dst_pb, rs_pb, deg, csr_pb);

    // ---- relation 'posts': tweet side ----
    seg_mean_csr_kernel<<<gSM, 256, 0, stream>>>(x_user, csr_posts, rs_posts, neigh);
    gemm_l1_kernel<<<gG, 256, 0, stream>>>(x_tweet, neigh, w1ps, w1pn, b1ps, b1pn,
                                           w2ps, w2bn, dself_t, scross_t);

    // ---- relation 'posted_by': user side ----
    seg_mean_csr_kernel<<<gSM, 256, 0, stream>>>(x_tweet, csr_pb, rs_pb, neigh);
    gemm_l1_kernel<<<gG, 256, 0, stream>>>(x_user, neigh, w1bs, w1bn, b1bs, b1bn,
                                           w2bs, w2pn, dself_u, scross_u);

    // ---- layer-2 neighbor terms (scalar seg means over same CSRs) ----
    scalar_seg_csr_kernel<<<gN, 256, 0, stream>>>(scross_u, csr_posts, rs_posts, smean_t);
    scalar_seg_csr_kernel<<<gN, 256, 0, stream>>>(scross_t, csr_pb, rs_pb, smean_u);

    finalize_kernel<<<gN, 256, 0, stream>>>(dself_u, smean_u, b2bs, b2bn,
                                            dself_t, smean_t, b2ps, b2pn, out);
}

// Round 3
// 290.344 us; speedup vs baseline: 7.0398x; 1.4682x over previous
//
#include <hip/hip_runtime.h>

#define N_NODES 100000
#define N_EDGES 500000
#define DIM 128
#define SCAN_BLOCKS ((N_NODES + 255) / 256)   // 391

typedef __attribute__((ext_vector_type(8))) short short8;   // 8 bf16 = 4 VGPRs
typedef __attribute__((ext_vector_type(4))) float f32x4;

__device__ __forceinline__ ushort f2bf(float f) {
    unsigned u = __float_as_uint(f);
    u += 0x7FFF + ((u >> 16) & 1);   // round-to-nearest-even
    return (ushort)(u >> 16);
}

// ---------------- CSR build ----------------

__global__ __launch_bounds__(256) void hist_kernel(const int* __restrict__ dst,
                                                   int* __restrict__ deg) {
    int e = blockIdx.x * 256 + threadIdx.x;
    if (e < N_EDGES) atomicAdd(&deg[dst[e]], 1);
}

__global__ __launch_bounds__(256) void scan_block_kernel(const int* __restrict__ deg,
                                                         int* __restrict__ excl,
                                                         int* __restrict__ bsums) {
    __shared__ int tmp[256];
    int t = threadIdx.x;
    int i = blockIdx.x * 256 + t;
    int v = (i < N_NODES) ? deg[i] : 0;
    tmp[t] = v;
    __syncthreads();
#pragma unroll
    for (int off = 1; off < 256; off <<= 1) {
        int x = (t >= off) ? tmp[t - off] : 0;
        __syncthreads();
        tmp[t] += x;
        __syncthreads();
    }
    if (i < N_NODES) excl[i] = tmp[t] - v;
    if (t == 255) bsums[blockIdx.x] = tmp[255];
}

__global__ __launch_bounds__(512) void scan_sums_kernel(int* __restrict__ bsums, int nb) {
    __shared__ int tmp[512];
    int t = threadIdx.x;
    int v = (t < nb) ? bsums[t] : 0;
    tmp[t] = v;
    __syncthreads();
#pragma unroll
    for (int off = 1; off < 512; off <<= 1) {
        int x = (t >= off) ? tmp[t - off] : 0;
        __syncthreads();
        tmp[t] += x;
        __syncthreads();
    }
    if (t < nb) bsums[t] = tmp[t] - v;
}

__global__ __launch_bounds__(256) void scan_add_kernel(int* __restrict__ excl,
                                                       const int* __restrict__ bsums) {
    int i = blockIdx.x * 256 + threadIdx.x;
    if (i < N_NODES) excl[i] += bsums[blockIdx.x];
}

__global__ __launch_bounds__(256) void scatter_kernel(const int* __restrict__ src,
                                                      const int* __restrict__ dst,
                                                      const int* __restrict__ rs,
                                                      int* __restrict__ cursor,
                                                      int* __restrict__ csr) {
    int e = blockIdx.x * 256 + threadIdx.x;
    if (e < N_EDGES) {
        int d = dst[e];
        int p = atomicAdd(&cursor[d], 1);
        csr[rs[d] + p] = src[e];
    }
}

// ---------------- weight f32 -> bf16 conversion ----------------
__global__ __launch_bounds__(256) void cvtw_kernel(
    const float* __restrict__ w0, const float* __restrict__ w1,
    const float* __restrict__ w2, const float* __restrict__ w3,
    ushort* __restrict__ o0, ushort* __restrict__ o1,
    ushort* __restrict__ o2, ushort* __restrict__ o3) {
    int a = blockIdx.y;
    const float* in = (a == 0) ? w0 : (a == 1) ? w1 : (a == 2) ? w2 : w3;
    ushort* out = (a == 0) ? o0 : (a == 1) ? o1 : (a == 2) ? o2 : o3;
    int i = (blockIdx.x * 256 + threadIdx.x) * 4;   // 16 blocks x 256 thr x 4 = 16384
    float4 v = *reinterpret_cast<const float4*>(&in[i]);
    ushort4 u = make_ushort4(f2bf(v.x), f2bf(v.y), f2bf(v.z), f2bf(v.w));
    *reinterpret_cast<ushort4*>(&out[i]) = u;
}

// ---------------- segment mean via CSR (f32 gather -> bf16 output) ----------------
__global__ __launch_bounds__(256) void seg_mean_csr_kernel(const float* __restrict__ x,
                                                           const int* __restrict__ csr,
                                                           const int* __restrict__ rs,
                                                           ushort* __restrict__ outbf) {
    int idx = blockIdx.x * 256 + threadIdx.x;
    int node = idx >> 5;
    if (node >= N_NODES) return;
    int f = (idx & 31) << 2;
    int beg = rs[node];
    int end = (node == N_NODES - 1) ? N_EDGES : rs[node + 1];
    float4 acc = make_float4(0.f, 0.f, 0.f, 0.f);
    for (int e = beg; e < end; ++e) {
        int s = csr[e];  // broadcast across 32 lanes
        float4 v = *reinterpret_cast<const float4*>(&x[s * DIM + f]);
        acc.x += v.x; acc.y += v.y; acc.z += v.z; acc.w += v.w;
    }
    float r = 1.0f / fmaxf((float)(end - beg), 1.0f);
    ushort4 u = make_ushort4(f2bf(acc.x * r), f2bf(acc.y * r),
                             f2bf(acc.z * r), f2bf(acc.w * r));
    *reinterpret_cast<ushort4*>(&outbf[node * DIM + f]) = u;
}

// Layer-2 scalar segment mean (linearity: seg_mean(h)@w2 = seg_mean(h@w2)).
__global__ __launch_bounds__(256) void scalar_seg_csr_kernel(const float* __restrict__ sval,
                                                             const int* __restrict__ csr,
                                                             const int* __restrict__ rs,
                                                             float* __restrict__ smean) {
    int node = blockIdx.x * 256 + threadIdx.x;
    if (node >= N_NODES) return;
    int beg = rs[node];
    int end = (node == N_NODES - 1) ? N_EDGES : rs[node + 1];
    float a = 0.f;
    for (int e = beg; e < end; ++e) a += sval[csr[e]];
    smean[node] = a / fmaxf((float)(end - beg), 1.0f);
}

// ---------------- fused layer-1 MFMA GEMM + layer-2 dots ----------------
// h = relu(Xs@Ws.T + bs + Nm@Wn.T + bn); epilogue: dself=h·w2a, dcross=h·w2b.
// 128x128 tile, 4 waves (2x2 of 64x64), K=256 (self 0..127, neigh 128..255), BK=64.
// LDS tiles [row][64] bf16, XOR-swizzled: byte_in_row ^= (row&7)<<4 (2-way residual = free).
__global__ __launch_bounds__(256) void gemm_mfma_kernel(
    const float* __restrict__ Xs,      // [N][128] f32 self features
    const ushort* __restrict__ Nm,     // [N][128] bf16 neighbor means
    const ushort* __restrict__ Wsbf,   // [128][128] bf16 (row-major [out][in])
    const ushort* __restrict__ Wnbf,
    const float* __restrict__ bs, const float* __restrict__ bn,
    const float* __restrict__ w2a, const float* __restrict__ w2b,
    float* __restrict__ dself, float* __restrict__ dcross) {
    __shared__ ushort sA[128 * 64];
    __shared__ ushort sB[128 * 64];
    __shared__ float pS[2][2][128];   // [wc][pa/pb][row]

    const int tid = threadIdx.x;
    const int lane = tid & 63;
    const int wid = tid >> 6;
    const int wr = wid >> 1, wc = wid & 1;
    const int lr = lane & 15, lg = lane >> 4;
    const int row0 = blockIdx.x * 128;

    f32x4 acc[4][4];
#pragma unroll
    for (int i = 0; i < 4; ++i)
#pragma unroll
        for (int j = 0; j < 4; ++j) acc[i][j] = (f32x4){0.f, 0.f, 0.f, 0.f};

    const int r = tid >> 1;         // staging row (A) / col (B): 0..127
    const int hh = tid & 1;         // which 32-k half of the BK=64 chunk
    const int grow = row0 + r;
    const int swzr = (r & 7) << 4;

    for (int kb = 0; kb < 256; kb += 64) {
        const int kg = kb & 127;
        const bool self = (kb < 128);
        __syncthreads();
        // ---- stage A [128 rows][64 k] bf16 ----
        if (self) {
            const float4* g = reinterpret_cast<const float4*>(Xs);
#pragma unroll
            for (int q = 0; q < 4; ++q) {
                float4 v0 = make_float4(0.f, 0.f, 0.f, 0.f), v1 = v0;
                if (grow < N_NODES) {
                    size_t bi = ((size_t)grow * DIM + kg + hh * 32 + q * 8) >> 2;
                    v0 = g[bi];
                    v1 = g[bi + 1];
                }
                union { ushort s[8]; uint4 v; } u;
                u.s[0] = f2bf(v0.x); u.s[1] = f2bf(v0.y);
                u.s[2] = f2bf(v0.z); u.s[3] = f2bf(v0.w);
                u.s[4] = f2bf(v1.x); u.s[5] = f2bf(v1.y);
                u.s[6] = f2bf(v1.z); u.s[7] = f2bf(v1.w);
                int byte = (hh * 64 + q * 16) ^ swzr;
                *reinterpret_cast<uint4*>(&sA[r * 64 + (byte >> 1)]) = u.v;
            }
        } else {
            const uint4* g = reinterpret_cast<const uint4*>(Nm);
#pragma unroll
            for (int q = 0; q < 4; ++q) {
                uint4 v = make_uint4(0, 0, 0, 0);
                if (grow < N_NODES)
                    v = g[((size_t)grow * DIM + kg + hh * 32 + q * 8) >> 3];
                int byte = (hh * 64 + q * 16) ^ swzr;
                *reinterpret_cast<uint4*>(&sA[r * 64 + (byte >> 1)]) = v;
            }
        }
        // ---- stage B [128 cols][64 k] bf16 ----
        {
            const uint4* g = reinterpret_cast<const uint4*>(self ? Wsbf : Wnbf);
#pragma unroll
            for (int q = 0; q < 4; ++q) {
                uint4 v = g[(r * DIM + kg + hh * 32 + q * 8) >> 3];
                int byte = (hh * 64 + q * 16) ^ swzr;
                *reinterpret_cast<uint4*>(&sB[r * 64 + (byte >> 1)]) = v;
            }
        }
        __syncthreads();
        // ---- MFMA: 2 k-steps x 4x4 fragments ----
#pragma unroll
        for (int ks = 0; ks < 2; ++ks) {
            short8 a[4], b[4];
#pragma unroll
            for (int fm = 0; fm < 4; ++fm) {
                int rr = wr * 64 + fm * 16 + lr;
                int byte = (ks * 64 + lg * 16) ^ ((rr & 7) << 4);
                a[fm] = *reinterpret_cast<const short8*>(&sA[rr * 64 + (byte >> 1)]);
            }
#pragma unroll
            for (int fn = 0; fn < 4; ++fn) {
                int cc = wc * 64 + fn * 16 + lr;
                int byte = (ks * 64 + lg * 16) ^ ((cc & 7) << 4);
                b[fn] = *reinterpret_cast<const short8*>(&sB[cc * 64 + (byte >> 1)]);
            }
#pragma unroll
            for (int fm = 0; fm < 4; ++fm)
#pragma unroll
                for (int fn = 0; fn < 4; ++fn)
                    acc[fm][fn] = __builtin_amdgcn_mfma_f32_16x16x32_bf16(
                        a[fm], b[fn], acc[fm][fn], 0, 0, 0);
        }
    }

    // ---- epilogue: bias + relu + two layer-2 dots (f32), no h materialization ----
    float bias[4], wa[4], wb[4];
#pragma unroll
    for (int fn = 0; fn < 4; ++fn) {
        int c = wc * 64 + fn * 16 + lr;
        bias[fn] = bs[c] + bn[c];
        wa[fn] = w2a[c];
        wb[fn] = w2b[c];
    }
#pragma unroll
    for (int fm = 0; fm < 4; ++fm) {
#pragma unroll
        for (int reg = 0; reg < 4; ++reg) {
            float pa = 0.f, pb = 0.f;
#pragma unroll
            for (int fn = 0; fn < 4; ++fn) {
                float h = fmaxf(acc[fm][fn][reg] + bias[fn], 0.f);
                pa = fmaf(h, wa[fn], pa);
                pb = fmaf(h, wb[fn], pb);
            }
#pragma unroll
            for (int m = 1; m < 16; m <<= 1) {   // reduce over lr (col groups)
                pa += __shfl_xor(pa, m);
                pb += __shfl_xor(pb, m);
            }
            if (lr == 0) {
                int rloc = wr * 64 + fm * 16 + lg * 4 + reg;  // C/D: row=(lane>>4)*4+reg
                pS[wc][0][rloc] = pa;
                pS[wc][1][rloc] = pb;
            }
        }
    }
    __syncthreads();
    if (tid < 128) {
        int go = row0 + tid;
        if (go < N_NODES) {
            dself[go] = pS[0][0][tid] + pS[1][0][tid];
            dcross[go] = pS[0][1][tid] + pS[1][1][tid];
        }
    }
}

__global__ __launch_bounds__(256) void finalize_kernel(
    const float* __restrict__ dself_u, const float* __restrict__ smean_u,
    const float* __restrict__ b2bs, const float* __restrict__ b2bn,
    const float* __restrict__ dself_t, const float* __restrict__ smean_t,
    const float* __restrict__ b2ps, const float* __restrict__ b2pn,
    float* __restrict__ out) {
    int i = blockIdx.x * 256 + threadIdx.x;
    if (i >= N_NODES) return;
    out[i] = dself_u[i] + smean_u[i] + b2bs[0] + b2bn[0];
    out[N_NODES + i] = dself_t[i] + smean_t[i] + b2ps[0] + b2pn[0];
}

extern "C" void kernel_launch(void* const* d_in, const int* in_sizes, int n_in,
                              void* d_out, int out_size, void* d_ws, size_t ws_size,
                              hipStream_t stream) {
    const float* x_user  = (const float*)d_in[0];
    const float* x_tweet = (const float*)d_in[1];
    const float* w1ps = (const float*)d_in[2];  const float* b1ps = (const float*)d_in[3];
    const float* w1pn = (const float*)d_in[4];  const float* b1pn = (const float*)d_in[5];
    const float* w1bs = (const float*)d_in[6];  const float* b1bs = (const float*)d_in[7];
    const float* w1bn = (const float*)d_in[8];  const float* b1bn = (const float*)d_in[9];
    const float* w2ps = (const float*)d_in[10]; const float* b2ps = (const float*)d_in[11];
    const float* w2pn = (const float*)d_in[12]; const float* b2pn = (const float*)d_in[13];
    const float* w2bs = (const float*)d_in[14]; const float* b2bs = (const float*)d_in[15];
    const float* w2bn = (const float*)d_in[16]; const float* b2bn = (const float*)d_in[17];
    const int* src_posts = (const int*)d_in[18];
    const int* dst_posts = (const int*)d_in[19];
    const int* src_pb    = (const int*)d_in[20];
    const int* dst_pb    = (const int*)d_in[21];
    float* out = (float*)d_out;

    // workspace layout (all regions 16B-aligned)
    char* wsb = (char*)d_ws;
    ushort* nbf     = (ushort*)wsb;   wsb += (size_t)N_NODES * DIM * 2;  // bf16 neigh mean
    int* csr_posts  = (int*)wsb;      wsb += (size_t)N_EDGES * 4;
    int* csr_pb     = (int*)wsb;      wsb += (size_t)N_EDGES * 4;
    int* rs_posts   = (int*)wsb;      wsb += (size_t)(N_NODES + 4) * 4;
    int* rs_pb      = (int*)wsb;      wsb += (size_t)(N_NODES + 4) * 4;
    int* deg        = (int*)wsb;      wsb += (size_t)N_NODES * 4;        // also cursor
    int* bsums      = (int*)wsb;      wsb += 512 * 4;
    ushort* wbf_ps  = (ushort*)wsb;   wsb += (size_t)DIM * DIM * 2;
    ushort* wbf_pn  = (ushort*)wsb;   wsb += (size_t)DIM * DIM * 2;
    ushort* wbf_bs  = (ushort*)wsb;   wsb += (size_t)DIM * DIM * 2;
    ushort* wbf_bn  = (ushort*)wsb;   wsb += (size_t)DIM * DIM * 2;
    float* dself_t  = (float*)wsb;    wsb += (size_t)N_NODES * 4;
    float* scross_t = (float*)wsb;    wsb += (size_t)N_NODES * 4;
    float* dself_u  = (float*)wsb;    wsb += (size_t)N_NODES * 4;
    float* scross_u = (float*)wsb;    wsb += (size_t)N_NODES * 4;
    float* smean_t  = (float*)wsb;    wsb += (size_t)N_NODES * 4;
    float* smean_u  = (float*)wsb;    wsb += (size_t)N_NODES * 4;

    const int gE = (N_EDGES + 255) / 256;
    const int gN = (N_NODES + 255) / 256;
    const int gSM = (N_NODES * 32 + 255) / 256;
    const int gG = (N_NODES + 127) / 128;   // 782

    // ---- weights -> bf16 (once) ----
    cvtw_kernel<<<dim3(16, 4), 256, 0, stream>>>(w1ps, w1pn, w1bs, w1bn,
                                                 wbf_ps, wbf_pn, wbf_bs, wbf_bn);

    // ---- build CSR for 'posts' (grouped by dst_posts) ----
    hipMemsetAsync(deg, 0, N_NODES * sizeof(int), stream);
    hist_kernel<<<gE, 256, 0, stream>>>(dst_posts, deg);
    scan_block_kernel<<<SCAN_BLOCKS, 256, 0, stream>>>(deg, rs_posts, bsums);
    scan_sums_kernel<<<1, 512, 0, stream>>>(bsums, SCAN_BLOCKS);
    scan_add_kernel<<<SCAN_BLOCKS, 256, 0, stream>>>(rs_posts, bsums);
    hipMemsetAsync(deg, 0, N_NODES * sizeof(int), stream);
    scatter_kernel<<<gE, 256, 0, stream>>>(src_posts, dst_posts, rs_posts, deg, csr_posts);

    // ---- build CSR for 'posted_by' ----
    hipMemsetAsync(deg, 0, N_NODES * sizeof(int), stream);
    hist_kernel<<<gE, 256, 0, stream>>>(dst_pb, deg);
    scan_block_kernel<<<SCAN_BLOCKS, 256, 0, stream>>>(deg, rs_pb, bsums);
    scan_sums_kernel<<<1, 512, 0, stream>>>(bsums, SCAN_BLOCKS);
    scan_add_kernel<<<SCAN_BLOCKS, 256, 0, stream>>>(rs_pb, bsums);
    hipMemsetAsync(deg, 0, N_NODES * sizeof(int), stream);
    scatter_kernel<<<gE, 256, 0, stream>>>(src_pb, dst_pb, rs_pb, deg, csr_pb);

    // ---- relation 'posts': tweet side ----
    seg_mean_csr_kernel<<<gSM, 256, 0, stream>>>(x_user, csr_posts, rs_posts, nbf);
    gemm_mfma_kernel<<<gG, 256, 0, stream>>>(x_tweet, nbf, wbf_ps, wbf_pn,
                                             b1ps, b1pn, w2ps, w2bn, dself_t, scross_t);

    // ---- relation 'posted_by': user side ----
    seg_mean_csr_kernel<<<gSM, 256, 0, stream>>>(x_tweet, csr_pb, rs_pb, nbf);
    gemm_mfma_kernel<<<gG, 256, 0, stream>>>(x_user, nbf, wbf_bs, wbf_bn,
                                             b1bs, b1bn, w2bs, w2pn, dself_u, scross_u);

    // ---- layer-2 neighbor terms (scalar seg means over same CSRs) ----
    scalar_seg_csr_kernel<<<gN, 256, 0, stream>>>(scross_u, csr_posts, rs_posts, smean_t);
    scalar_seg_csr_kernel<<<gN, 256, 0, stream>>>(scross_t, csr_pb, rs_pb, smean_u);

    finalize_kernel<<<gN, 256, 0, stream>>>(dself_u, smean_u, b2bs, b2bn,
                                            dself_t, smean_t, b2ps, b2pn, out);
}

// Round 4
// 263.647 us; speedup vs baseline: 7.7526x; 1.1013x over previous
//
#include <hip/hip_runtime.h>

#define N_NODES 100000
#define N_EDGES 500000
#define DIM 128
#define SCAN_BLOCKS ((N_NODES + 255) / 256)   // 391

typedef __attribute__((ext_vector_type(8))) short short8;   // 8 bf16 = 4 VGPRs
typedef __attribute__((ext_vector_type(4))) float f32x4;

__device__ __forceinline__ ushort f2bf(float f) {
    unsigned u = __float_as_uint(f);
    u += 0x7FFF + ((u >> 16) & 1);   // round-to-nearest-even
    return (ushort)(u >> 16);
}
__device__ __forceinline__ float bf2f(ushort s) {
    return __uint_as_float(((unsigned)s) << 16);
}

// ---------------- CSR build (both relations batched via blockIdx.y) ----------------

__global__ __launch_bounds__(256) void hist2_kernel(const int* __restrict__ d0,
                                                    const int* __restrict__ d1,
                                                    int* __restrict__ deg2) {
    int e = blockIdx.x * 256 + threadIdx.x;
    const int* dst = blockIdx.y ? d1 : d0;
    if (e < N_EDGES) atomicAdd(&deg2[blockIdx.y * N_NODES + dst[e]], 1);
}

__global__ __launch_bounds__(256) void scan_block2_kernel(const int* __restrict__ deg2,
                                                          int* __restrict__ excl2,
                                                          int* __restrict__ bsums2) {
    const int rel = blockIdx.y;
    const int* deg = deg2 + rel * N_NODES;
    int* excl = excl2 + rel * N_NODES;
    int* bsums = bsums2 + rel * 512;
    __shared__ int tmp[256];
    int t = threadIdx.x;
    int i = blockIdx.x * 256 + t;
    int v = (i < N_NODES) ? deg[i] : 0;
    tmp[t] = v;
    __syncthreads();
#pragma unroll
    for (int off = 1; off < 256; off <<= 1) {
        int x = (t >= off) ? tmp[t - off] : 0;
        __syncthreads();
        tmp[t] += x;
        __syncthreads();
    }
    if (i < N_NODES) excl[i] = tmp[t] - v;
    if (t == 255) bsums[blockIdx.x] = tmp[255];
}

__global__ __launch_bounds__(512) void scan_sums2_kernel(int* __restrict__ bsums2, int nb) {
    int* bsums = bsums2 + blockIdx.y * 512;
    __shared__ int tmp[512];
    int t = threadIdx.x;
    int v = (t < nb) ? bsums[t] : 0;
    tmp[t] = v;
    __syncthreads();
#pragma unroll
    for (int off = 1; off < 512; off <<= 1) {
        int x = (t >= off) ? tmp[t - off] : 0;
        __syncthreads();
        tmp[t] += x;
        __syncthreads();
    }
    if (t < nb) bsums[t] = tmp[t] - v;
}

__global__ __launch_bounds__(256) void scan_add2_kernel(int* __restrict__ excl2,
                                                        const int* __restrict__ bsums2) {
    const int rel = blockIdx.y;
    int i = blockIdx.x * 256 + threadIdx.x;
    if (i < N_NODES) excl2[rel * N_NODES + i] += bsums2[rel * 512 + blockIdx.x];
}

__global__ __launch_bounds__(256) void scatter2_kernel(const int* __restrict__ s0,
                                                       const int* __restrict__ d0,
                                                       const int* __restrict__ s1,
                                                       const int* __restrict__ d1,
                                                       const int* __restrict__ rs2,
                                                       int* __restrict__ cursor2,
                                                       int* __restrict__ csr2) {
    const int rel = blockIdx.y;
    const int* src = rel ? s1 : s0;
    const int* dst = rel ? d1 : d0;
    int e = blockIdx.x * 256 + threadIdx.x;
    if (e < N_EDGES) {
        int d = dst[e];
        int p = atomicAdd(&cursor2[rel * N_NODES + d], 1);
        csr2[rel * N_EDGES + rs2[rel * N_NODES + d] + p] = src[e];
    }
}

// ---------------- dtype conversions ----------------

__global__ __launch_bounds__(256) void cvtw_kernel(
    const float* __restrict__ w0, const float* __restrict__ w1,
    const float* __restrict__ w2, const float* __restrict__ w3,
    ushort* __restrict__ o0, ushort* __restrict__ o1,
    ushort* __restrict__ o2, ushort* __restrict__ o3) {
    int a = blockIdx.y;
    const float* in = (a == 0) ? w0 : (a == 1) ? w1 : (a == 2) ? w2 : w3;
    ushort* out = (a == 0) ? o0 : (a == 1) ? o1 : (a == 2) ? o2 : o3;
    int i = (blockIdx.x * 256 + threadIdx.x) * 4;
    float4 v = *reinterpret_cast<const float4*>(&in[i]);
    ushort4 u = make_ushort4(f2bf(v.x), f2bf(v.y), f2bf(v.z), f2bf(v.w));
    *reinterpret_cast<ushort4*>(&out[i]) = u;
}

// features f32 -> bf16 (both node types, blockIdx.y selects)
__global__ __launch_bounds__(256) void cvtx_kernel(const float* __restrict__ x0,
                                                   const float* __restrict__ x1,
                                                   ushort* __restrict__ o0,
                                                   ushort* __restrict__ o1) {
    const float* in = blockIdx.y ? x1 : x0;
    ushort* out = blockIdx.y ? o1 : o0;
    int i = (blockIdx.x * 256 + threadIdx.x) * 4;   // 12500 blocks x 1024 = 12.8M
    float4 v = *reinterpret_cast<const float4*>(&in[i]);
    ushort4 u = make_ushort4(f2bf(v.x), f2bf(v.y), f2bf(v.z), f2bf(v.w));
    *reinterpret_cast<ushort4*>(&out[i]) = u;
}

// ---------------- segment means via CSR (no atomics) ----------------

// bf16 gather: 16 lanes per node, each lane owns 8 contiguous feats (ushort8 = 16B).
__global__ __launch_bounds__(256) void seg_mean_bf16_kernel(const ushort* __restrict__ x,
                                                            const int* __restrict__ csr,
                                                            const int* __restrict__ rs,
                                                            ushort* __restrict__ outbf) {
    int idx = blockIdx.x * 256 + threadIdx.x;
    int node = idx >> 4;
    if (node >= N_NODES) return;
    int f = (idx & 15) << 3;
    int beg = rs[node];
    int end = (node == N_NODES - 1) ? N_EDGES : rs[node + 1];
    float acc[8];
#pragma unroll
    for (int j = 0; j < 8; ++j) acc[j] = 0.f;
    for (int e = beg; e < end; ++e) {
        int s = csr[e];  // broadcast across the 16-lane group
        short8 v = *reinterpret_cast<const short8*>(&x[(size_t)s * DIM + f]);
#pragma unroll
        for (int j = 0; j < 8; ++j) acc[j] += bf2f((ushort)v[j]);
    }
    float r = 1.0f / fmaxf((float)(end - beg), 1.0f);
    union { ushort s[8]; uint4 v; } u;
#pragma unroll
    for (int j = 0; j < 8; ++j) u.s[j] = f2bf(acc[j] * r);
    *reinterpret_cast<uint4*>(&outbf[(size_t)node * DIM + f]) = u.v;
}

// f32 fallback (when workspace too small for bf16 feature copies): 32 lanes/node.
__global__ __launch_bounds__(256) void seg_mean_csr_kernel(const float* __restrict__ x,
                                                           const int* __restrict__ csr,
                                                           const int* __restrict__ rs,
                                                           ushort* __restrict__ outbf) {
    int idx = blockIdx.x * 256 + threadIdx.x;
    int node = idx >> 5;
    if (node >= N_NODES) return;
    int f = (idx & 31) << 2;
    int beg = rs[node];
    int end = (node == N_NODES - 1) ? N_EDGES : rs[node + 1];
    float4 acc = make_float4(0.f, 0.f, 0.f, 0.f);
    for (int e = beg; e < end; ++e) {
        int s = csr[e];
        float4 v = *reinterpret_cast<const float4*>(&x[s * DIM + f]);
        acc.x += v.x; acc.y += v.y; acc.z += v.z; acc.w += v.w;
    }
    float r = 1.0f / fmaxf((float)(end - beg), 1.0f);
    ushort4 u = make_ushort4(f2bf(acc.x * r), f2bf(acc.y * r),
                             f2bf(acc.z * r), f2bf(acc.w * r));
    *reinterpret_cast<ushort4*>(&outbf[node * DIM + f]) = u;
}

// Layer-2 scalar segment means, both relations (linearity: seg_mean(h)@w2 = seg_mean(h@w2)).
__global__ __launch_bounds__(256) void scalar_seg2_kernel(const float* __restrict__ sv0,
                                                          const float* __restrict__ sv1,
                                                          const int* __restrict__ csr2,
                                                          const int* __restrict__ rs2,
                                                          float* __restrict__ sm0,
                                                          float* __restrict__ sm1) {
    const int rel = blockIdx.y;
    const float* sval = rel ? sv1 : sv0;
    const int* csr = csr2 + (size_t)rel * N_EDGES;
    const int* rs = rs2 + rel * N_NODES;
    float* smean = rel ? sm1 : sm0;
    int node = blockIdx.x * 256 + threadIdx.x;
    if (node >= N_NODES) return;
    int beg = rs[node];
    int end = (node == N_NODES - 1) ? N_EDGES : rs[node + 1];
    float a = 0.f;
    for (int e = beg; e < end; ++e) a += sval[csr[e]];
    smean[node] = a / fmaxf((float)(end - beg), 1.0f);
}

// ---------------- fused layer-1 MFMA GEMM + layer-2 dots ----------------
// h = relu(Xs@Ws.T + bs + Nm@Wn.T + bn); epilogue: dself=h·w2a, dcross=h·w2b.
// 128x128 tile, 4 waves (2x2 of 64x64), K=256 (self 0..127, neigh 128..255), BK=64.
// LDS tiles [row][64] bf16, XOR-swizzled: byte_in_row ^= (row&7)<<4.
__global__ __launch_bounds__(256) void gemm_mfma_kernel(
    const float* __restrict__ Xs,      // [N][128] f32 self features
    const ushort* __restrict__ Nm,     // [N][128] bf16 neighbor means
    const ushort* __restrict__ Wsbf,   // [128][128] bf16 (row-major [out][in])
    const ushort* __restrict__ Wnbf,
    const float* __restrict__ bs, const float* __restrict__ bn,
    const float* __restrict__ w2a, const float* __restrict__ w2b,
    float* __restrict__ dself, float* __restrict__ dcross) {
    __shared__ ushort sA[128 * 64];
    __shared__ ushort sB[128 * 64];
    __shared__ float pS[2][2][128];   // [wc][pa/pb][row]

    const int tid = threadIdx.x;
    const int lane = tid & 63;
    const int wid = tid >> 6;
    const int wr = wid >> 1, wc = wid & 1;
    const int lr = lane & 15, lg = lane >> 4;
    const int row0 = blockIdx.x * 128;

    f32x4 acc[4][4];
#pragma unroll
    for (int i = 0; i < 4; ++i)
#pragma unroll
        for (int j = 0; j < 4; ++j) acc[i][j] = (f32x4){0.f, 0.f, 0.f, 0.f};

    const int r = tid >> 1;
    const int hh = tid & 1;
    const int grow = row0 + r;
    const int swzr = (r & 7) << 4;

    for (int kb = 0; kb < 256; kb += 64) {
        const int kg = kb & 127;
        const bool self = (kb < 128);
        __syncthreads();
        // ---- stage A [128 rows][64 k] bf16 ----
        if (self) {
            const float4* g = reinterpret_cast<const float4*>(Xs);
#pragma unroll
            for (int q = 0; q < 4; ++q) {
                float4 v0 = make_float4(0.f, 0.f, 0.f, 0.f), v1 = v0;
                if (grow < N_NODES) {
                    size_t bi = ((size_t)grow * DIM + kg + hh * 32 + q * 8) >> 2;
                    v0 = g[bi];
                    v1 = g[bi + 1];
                }
                union { ushort s[8]; uint4 v; } u;
                u.s[0] = f2bf(v0.x); u.s[1] = f2bf(v0.y);
                u.s[2] = f2bf(v0.z); u.s[3] = f2bf(v0.w);
                u.s[4] = f2bf(v1.x); u.s[5] = f2bf(v1.y);
                u.s[6] = f2bf(v1.z); u.s[7] = f2bf(v1.w);
                int byte = (hh * 64 + q * 16) ^ swzr;
                *reinterpret_cast<uint4*>(&sA[r * 64 + (byte >> 1)]) = u.v;
            }
        } else {
            const uint4* g = reinterpret_cast<const uint4*>(Nm);
#pragma unroll
            for (int q = 0; q < 4; ++q) {
                uint4 v = make_uint4(0, 0, 0, 0);
                if (grow < N_NODES)
                    v = g[((size_t)grow * DIM + kg + hh * 32 + q * 8) >> 3];
                int byte = (hh * 64 + q * 16) ^ swzr;
                *reinterpret_cast<uint4*>(&sA[r * 64 + (byte >> 1)]) = v;
            }
        }
        // ---- stage B [128 cols][64 k] bf16 ----
        {
            const uint4* g = reinterpret_cast<const uint4*>(self ? Wsbf : Wnbf);
#pragma unroll
            for (int q = 0; q < 4; ++q) {
                uint4 v = g[(r * DIM + kg + hh * 32 + q * 8) >> 3];
                int byte = (hh * 64 + q * 16) ^ swzr;
                *reinterpret_cast<uint4*>(&sB[r * 64 + (byte >> 1)]) = v;
            }
        }
        __syncthreads();
#pragma unroll
        for (int ks = 0; ks < 2; ++ks) {
            short8 a[4], b[4];
#pragma unroll
            for (int fm = 0; fm < 4; ++fm) {
                int rr = wr * 64 + fm * 16 + lr;
                int byte = (ks * 64 + lg * 16) ^ ((rr & 7) << 4);
                a[fm] = *reinterpret_cast<const short8*>(&sA[rr * 64 + (byte >> 1)]);
            }
#pragma unroll
            for (int fn = 0; fn < 4; ++fn) {
                int cc = wc * 64 + fn * 16 + lr;
                int byte = (ks * 64 + lg * 16) ^ ((cc & 7) << 4);
                b[fn] = *reinterpret_cast<const short8*>(&sB[cc * 64 + (byte >> 1)]);
            }
#pragma unroll
            for (int fm = 0; fm < 4; ++fm)
#pragma unroll
                for (int fn = 0; fn < 4; ++fn)
                    acc[fm][fn] = __builtin_amdgcn_mfma_f32_16x16x32_bf16(
                        a[fm], b[fn], acc[fm][fn], 0, 0, 0);
        }
    }

    float bias[4], wa[4], wb[4];
#pragma unroll
    for (int fn = 0; fn < 4; ++fn) {
        int c = wc * 64 + fn * 16 + lr;
        bias[fn] = bs[c] + bn[c];
        wa[fn] = w2a[c];
        wb[fn] = w2b[c];
    }
#pragma unroll
    for (int fm = 0; fm < 4; ++fm) {
#pragma unroll
        for (int reg = 0; reg < 4; ++reg) {
            float pa = 0.f, pb = 0.f;
#pragma unroll
            for (int fn = 0; fn < 4; ++fn) {
                float h = fmaxf(acc[fm][fn][reg] + bias[fn], 0.f);
                pa = fmaf(h, wa[fn], pa);
                pb = fmaf(h, wb[fn], pb);
            }
#pragma unroll
            for (int m = 1; m < 16; m <<= 1) {
                pa += __shfl_xor(pa, m);
                pb += __shfl_xor(pb, m);
            }
            if (lr == 0) {
                int rloc = wr * 64 + fm * 16 + lg * 4 + reg;
                pS[wc][0][rloc] = pa;
                pS[wc][1][rloc] = pb;
            }
        }
    }
    __syncthreads();
    if (tid < 128) {
        int go = row0 + tid;
        if (go < N_NODES) {
            dself[go] = pS[0][0][tid] + pS[1][0][tid];
            dcross[go] = pS[0][1][tid] + pS[1][1][tid];
        }
    }
}

__global__ __launch_bounds__(256) void finalize_kernel(
    const float* __restrict__ dself_u, const float* __restrict__ smean_u,
    const float* __restrict__ b2bs, const float* __restrict__ b2bn,
    const float* __restrict__ dself_t, const float* __restrict__ smean_t,
    const float* __restrict__ b2ps, const float* __restrict__ b2pn,
    float* __restrict__ out) {
    int i = blockIdx.x * 256 + threadIdx.x;
    if (i >= N_NODES) return;
    out[i] = dself_u[i] + smean_u[i] + b2bs[0] + b2bn[0];
    out[N_NODES + i] = dself_t[i] + smean_t[i] + b2ps[0] + b2pn[0];
}

extern "C" void kernel_launch(void* const* d_in, const int* in_sizes, int n_in,
                              void* d_out, int out_size, void* d_ws, size_t ws_size,
                              hipStream_t stream) {
    const float* x_user  = (const float*)d_in[0];
    const float* x_tweet = (const float*)d_in[1];
    const float* w1ps = (const float*)d_in[2];  const float* b1ps = (const float*)d_in[3];
    const float* w1pn = (const float*)d_in[4];  const float* b1pn = (const float*)d_in[5];
    const float* w1bs = (const float*)d_in[6];  const float* b1bs = (const float*)d_in[7];
    const float* w1bn = (const float*)d_in[8];  const float* b1bn = (const float*)d_in[9];
    const float* w2ps = (const float*)d_in[10]; const float* b2ps = (const float*)d_in[11];
    const float* w2pn = (const float*)d_in[12]; const float* b2pn = (const float*)d_in[13];
    const float* w2bs = (const float*)d_in[14]; const float* b2bs = (const float*)d_in[15];
    const float* w2bn = (const float*)d_in[16]; const float* b2bn = (const float*)d_in[17];
    const int* src_posts = (const int*)d_in[18];
    const int* dst_posts = (const int*)d_in[19];
    const int* src_pb    = (const int*)d_in[20];
    const int* dst_pb    = (const int*)d_in[21];
    float* out = (float*)d_out;

    // ---- workspace layout (16B aligned regions) ----
    char* wsb = (char*)d_ws;
    ushort* nbf     = (ushort*)wsb;   wsb += (size_t)N_NODES * DIM * 2;      // 25.6 MB
    int* csr2       = (int*)wsb;      wsb += (size_t)2 * N_EDGES * 4;        //  4.0 MB
    int* rs2        = (int*)wsb;      wsb += (size_t)2 * N_NODES * 4;        //  0.8 MB
    int* deg2       = (int*)wsb;      wsb += (size_t)2 * N_NODES * 4;        //  0.8 MB
    int* bsums2     = (int*)wsb;      wsb += 1024 * 4;
    ushort* wbf_ps  = (ushort*)wsb;   wsb += (size_t)DIM * DIM * 2;
    ushort* wbf_pn  = (ushort*)wsb;   wsb += (size_t)DIM * DIM * 2;
    ushort* wbf_bs  = (ushort*)wsb;   wsb += (size_t)DIM * DIM * 2;
    ushort* wbf_bn  = (ushort*)wsb;   wsb += (size_t)DIM * DIM * 2;
    float* dself_t  = (float*)wsb;    wsb += (size_t)N_NODES * 4;
    float* scross_t = (float*)wsb;    wsb += (size_t)N_NODES * 4;
    float* dself_u  = (float*)wsb;    wsb += (size_t)N_NODES * 4;
    float* scross_u = (float*)wsb;    wsb += (size_t)N_NODES * 4;
    float* smean_t  = (float*)wsb;    wsb += (size_t)N_NODES * 4;
    float* smean_u  = (float*)wsb;    wsb += (size_t)N_NODES * 4;
    // bf16 feature copies last, so the fallback path's footprint is unchanged
    ushort* xbf_u   = (ushort*)wsb;   wsb += (size_t)N_NODES * DIM * 2;      // 25.6 MB
    ushort* xbf_t   = (ushort*)wsb;   wsb += (size_t)N_NODES * DIM * 2;      // 25.6 MB
    const bool use_bf = ((size_t)(wsb - (char*)d_ws) <= ws_size);

    int* csr_posts = csr2;
    int* csr_pb    = csr2 + N_EDGES;
    int* rs_posts  = rs2;
    int* rs_pb     = rs2 + N_NODES;

    const int gE = (N_EDGES + 255) / 256;
    const int gN = (N_NODES + 255) / 256;
    const int gG = (N_NODES + 127) / 128;   // 782

    // ---- dtype conversions ----
    cvtw_kernel<<<dim3(16, 4), 256, 0, stream>>>(w1ps, w1pn, w1bs, w1bn,
                                                 wbf_ps, wbf_pn, wbf_bs, wbf_bn);
    if (use_bf)
        cvtx_kernel<<<dim3(12500, 2), 256, 0, stream>>>(x_user, x_tweet, xbf_u, xbf_t);

    // ---- build both CSRs (grouped by dst), batched ----
    hipMemsetAsync(deg2, 0, 2 * N_NODES * sizeof(int), stream);
    hist2_kernel<<<dim3(gE, 2), 256, 0, stream>>>(dst_posts, dst_pb, deg2);
    scan_block2_kernel<<<dim3(SCAN_BLOCKS, 2), 256, 0, stream>>>(deg2, rs2, bsums2);
    scan_sums2_kernel<<<dim3(1, 2), 512, 0, stream>>>(bsums2, SCAN_BLOCKS);
    scan_add2_kernel<<<dim3(SCAN_BLOCKS, 2), 256, 0, stream>>>(rs2, bsums2);
    hipMemsetAsync(deg2, 0, 2 * N_NODES * sizeof(int), stream);
    scatter2_kernel<<<dim3(gE, 2), 256, 0, stream>>>(src_posts, dst_posts, src_pb, dst_pb,
                                                     rs2, deg2, csr2);

    // ---- relation 'posts': tweet side ----
    if (use_bf)
        seg_mean_bf16_kernel<<<(N_NODES * 16 + 255) / 256, 256, 0, stream>>>(
            xbf_u, csr_posts, rs_posts, nbf);
    else
        seg_mean_csr_kernel<<<(N_NODES * 32 + 255) / 256, 256, 0, stream>>>(
            x_user, csr_posts, rs_posts, nbf);
    gemm_mfma_kernel<<<gG, 256, 0, stream>>>(x_tweet, nbf, wbf_ps, wbf_pn,
                                             b1ps, b1pn, w2ps, w2bn, dself_t, scross_t);

    // ---- relation 'posted_by': user side ----
    if (use_bf)
        seg_mean_bf16_kernel<<<(N_NODES * 16 + 255) / 256, 256, 0, stream>>>(
            xbf_t, csr_pb, rs_pb, nbf);
    else
        seg_mean_csr_kernel<<<(N_NODES * 32 + 255) / 256, 256, 0, stream>>>(
            x_tweet, csr_pb, rs_pb, nbf);
    gemm_mfma_kernel<<<gG, 256, 0, stream>>>(x_user, nbf, wbf_bs, wbf_bn,
                                             b1bs, b1bn, w2bs, w2pn, dself_u, scross_u);

    // ---- layer-2 neighbor terms (scalar seg means over same CSRs, batched) ----
    scalar_seg2_kernel<<<dim3(gN, 2), 256, 0, stream>>>(scross_u, scross_t, csr2, rs2,
                                                        smean_t, smean_u);

    finalize_kernel<<<gN, 256, 0, stream>>>(dself_u, smean_u, b2bs, b2bn,
                                            dself_t, smean_t, b2ps, b2pn, out);
}

// Round 5
// 223.057 us; speedup vs baseline: 9.1634x; 1.1820x over previous
//
#include <hip/hip_runtime.h>

#define N_NODES 100000
#define N_EDGES 500000
#define DIM 128

typedef __attribute__((ext_vector_type(8))) short short8;   // 8 bf16 = 4 VGPRs
typedef __attribute__((ext_vector_type(4))) float f32x4;

__device__ __forceinline__ ushort f2bf(float f) {
    unsigned u = __float_as_uint(f);
    u += 0x7FFF + ((u >> 16) & 1);   // round-to-nearest-even
    return (ushort)(u >> 16);
}
__device__ __forceinline__ float bf2f(ushort s) {
    return __uint_as_float(((unsigned)s) << 16);
}

// ---------------- per-node linked-list build (replaces hist+scan+scatter) ----------------
// head[d] = last edge id with dst d; entry[e] = {src[e], prev head}. One pass,
// atomicExch on L2-resident head (800 KB) + fully coalesced 8B entry writes.

__global__ __launch_bounds__(256) void build_lists2_kernel(
    const int* __restrict__ s0, const int* __restrict__ d0,
    const int* __restrict__ s1, const int* __restrict__ d1,
    int* __restrict__ head2, int2* __restrict__ entry2) {
    const int rel = blockIdx.y;
    const int* src = rel ? s1 : s0;
    const int* dst = rel ? d1 : d0;
    int* head = head2 + rel * N_NODES;
    int2* entry = entry2 + (size_t)rel * N_EDGES;
    int e = blockIdx.x * 256 + threadIdx.x;
    if (e < N_EDGES) {
        int d = dst[e];
        int old = atomicExch(&head[d], e);
        entry[e] = make_int2(src[e], old);
    }
}

// ---------------- dtype conversions ----------------

__global__ __launch_bounds__(256) void cvtw_kernel(
    const float* __restrict__ w0, const float* __restrict__ w1,
    const float* __restrict__ w2, const float* __restrict__ w3,
    ushort* __restrict__ o0, ushort* __restrict__ o1,
    ushort* __restrict__ o2, ushort* __restrict__ o3) {
    int a = blockIdx.y;
    const float* in = (a == 0) ? w0 : (a == 1) ? w1 : (a == 2) ? w2 : w3;
    ushort* out = (a == 0) ? o0 : (a == 1) ? o1 : (a == 2) ? o2 : o3;
    int i = (blockIdx.x * 256 + threadIdx.x) * 4;
    float4 v = *reinterpret_cast<const float4*>(&in[i]);
    ushort4 u = make_ushort4(f2bf(v.x), f2bf(v.y), f2bf(v.z), f2bf(v.w));
    *reinterpret_cast<ushort4*>(&out[i]) = u;
}

// features f32 -> bf16 (both node types, blockIdx.y selects)
__global__ __launch_bounds__(256) void cvtx_kernel(const float* __restrict__ x0,
                                                   const float* __restrict__ x1,
                                                   ushort* __restrict__ o0,
                                                   ushort* __restrict__ o1) {
    const float* in = blockIdx.y ? x1 : x0;
    ushort* out = blockIdx.y ? o1 : o0;
    int i = (blockIdx.x * 256 + threadIdx.x) * 4;
    float4 v = *reinterpret_cast<const float4*>(&in[i]);
    ushort4 u = make_ushort4(f2bf(v.x), f2bf(v.y), f2bf(v.z), f2bf(v.w));
    *reinterpret_cast<ushort4*>(&out[i]) = u;
}

// ---------------- segment means via list traversal (no atomics, no CSR) ----------------

// bf16 gather: 16 lanes per node, each lane owns 8 contiguous feats (16B loads).
__global__ __launch_bounds__(256) void seg_mean_bf16_list_kernel(
    const ushort* __restrict__ x, const int* __restrict__ head,
    const int2* __restrict__ entry, ushort* __restrict__ outbf) {
    int idx = blockIdx.x * 256 + threadIdx.x;
    int node = idx >> 4;
    if (node >= N_NODES) return;
    int f = (idx & 15) << 3;
    float acc[8];
#pragma unroll
    for (int j = 0; j < 8; ++j) acc[j] = 0.f;
    int cnt = 0;
    int e = head[node];
    while (e >= 0) {
        int2 nd = entry[e];   // one dependent 8B load per hop (broadcast in group)
        ++cnt;
        short8 v = *reinterpret_cast<const short8*>(&x[(size_t)nd.x * DIM + f]);
#pragma unroll
        for (int j = 0; j < 8; ++j) acc[j] += bf2f((ushort)v[j]);
        e = nd.y;
    }
    float r = 1.0f / fmaxf((float)cnt, 1.0f);
    union { ushort s[8]; uint4 v; } u;
#pragma unroll
    for (int j = 0; j < 8; ++j) u.s[j] = f2bf(acc[j] * r);
    *reinterpret_cast<uint4*>(&outbf[(size_t)node * DIM + f]) = u.v;
}

// f32 fallback (workspace too small for bf16 feature copies): 32 lanes/node.
__global__ __launch_bounds__(256) void seg_mean_f32_list_kernel(
    const float* __restrict__ x, const int* __restrict__ head,
    const int2* __restrict__ entry, ushort* __restrict__ outbf) {
    int idx = blockIdx.x * 256 + threadIdx.x;
    int node = idx >> 5;
    if (node >= N_NODES) return;
    int f = (idx & 31) << 2;
    float4 acc = make_float4(0.f, 0.f, 0.f, 0.f);
    int cnt = 0;
    int e = head[node];
    while (e >= 0) {
        int2 nd = entry[e];
        ++cnt;
        float4 v = *reinterpret_cast<const float4*>(&x[(size_t)nd.x * DIM + f]);
        acc.x += v.x; acc.y += v.y; acc.z += v.z; acc.w += v.w;
        e = nd.y;
    }
    float r = 1.0f / fmaxf((float)cnt, 1.0f);
    ushort4 u = make_ushort4(f2bf(acc.x * r), f2bf(acc.y * r),
                             f2bf(acc.z * r), f2bf(acc.w * r));
    *reinterpret_cast<ushort4*>(&outbf[(size_t)node * DIM + f]) = u;
}

// Layer-2 scalar segment means, both relations (linearity: seg_mean(h)@w2 = seg_mean(h@w2)).
__global__ __launch_bounds__(256) void scalar_seg2_list_kernel(
    const float* __restrict__ sv0, const float* __restrict__ sv1,
    const int* __restrict__ head2, const int2* __restrict__ entry2,
    float* __restrict__ sm0, float* __restrict__ sm1) {
    const int rel = blockIdx.y;
    const float* sval = rel ? sv1 : sv0;
    const int* head = head2 + rel * N_NODES;
    const int2* entry = entry2 + (size_t)rel * N_EDGES;
    float* smean = rel ? sm1 : sm0;
    int node = blockIdx.x * 256 + threadIdx.x;
    if (node >= N_NODES) return;
    float a = 0.f;
    int cnt = 0;
    int e = head[node];
    while (e >= 0) {
        int2 nd = entry[e];
        ++cnt;
        a += sval[nd.x];
        e = nd.y;
    }
    smean[node] = a / fmaxf((float)cnt, 1.0f);
}

// ---------------- fused layer-1 MFMA GEMM + layer-2 dots ----------------
// h = relu(Xs@Ws.T + bs + Nm@Wn.T + bn); epilogue: dself=h·w2a, dcross=h·w2b.
// 128x128 tile, 4 waves (2x2 of 64x64), K=256 (self 0..127, neigh 128..255), BK=64.
// LDS tiles [row][64] bf16, XOR-swizzled: byte_in_row ^= (row&7)<<4.
__global__ __launch_bounds__(256) void gemm_mfma_kernel(
    const float* __restrict__ Xs,      // [N][128] f32 self features
    const ushort* __restrict__ Nm,     // [N][128] bf16 neighbor means
    const ushort* __restrict__ Wsbf,   // [128][128] bf16 (row-major [out][in])
    const ushort* __restrict__ Wnbf,
    const float* __restrict__ bs, const float* __restrict__ bn,
    const float* __restrict__ w2a, const float* __restrict__ w2b,
    float* __restrict__ dself, float* __restrict__ dcross) {
    __shared__ ushort sA[128 * 64];
    __shared__ ushort sB[128 * 64];
    __shared__ float pS[2][2][128];   // [wc][pa/pb][row]

    const int tid = threadIdx.x;
    const int lane = tid & 63;
    const int wid = tid >> 6;
    const int wr = wid >> 1, wc = wid & 1;
    const int lr = lane & 15, lg = lane >> 4;
    const int row0 = blockIdx.x * 128;

    f32x4 acc[4][4];
#pragma unroll
    for (int i = 0; i < 4; ++i)
#pragma unroll
        for (int j = 0; j < 4; ++j) acc[i][j] = (f32x4){0.f, 0.f, 0.f, 0.f};

    const int r = tid >> 1;
    const int hh = tid & 1;
    const int grow = row0 + r;
    const int swzr = (r & 7) << 4;

    for (int kb = 0; kb < 256; kb += 64) {
        const int kg = kb & 127;
        const bool self = (kb < 128);
        __syncthreads();
        // ---- stage A [128 rows][64 k] bf16 ----
        if (self) {
            const float4* g = reinterpret_cast<const float4*>(Xs);
#pragma unroll
            for (int q = 0; q < 4; ++q) {
                float4 v0 = make_float4(0.f, 0.f, 0.f, 0.f), v1 = v0;
                if (grow < N_NODES) {
                    size_t bi = ((size_t)grow * DIM + kg + hh * 32 + q * 8) >> 2;
                    v0 = g[bi];
                    v1 = g[bi + 1];
                }
                union { ushort s[8]; uint4 v; } u;
                u.s[0] = f2bf(v0.x); u.s[1] = f2bf(v0.y);
                u.s[2] = f2bf(v0.z); u.s[3] = f2bf(v0.w);
                u.s[4] = f2bf(v1.x); u.s[5] = f2bf(v1.y);
                u.s[6] = f2bf(v1.z); u.s[7] = f2bf(v1.w);
                int byte = (hh * 64 + q * 16) ^ swzr;
                *reinterpret_cast<uint4*>(&sA[r * 64 + (byte >> 1)]) = u.v;
            }
        } else {
            const uint4* g = reinterpret_cast<const uint4*>(Nm);
#pragma unroll
            for (int q = 0; q < 4; ++q) {
                uint4 v = make_uint4(0, 0, 0, 0);
                if (grow < N_NODES)
                    v = g[((size_t)grow * DIM + kg + hh * 32 + q * 8) >> 3];
                int byte = (hh * 64 + q * 16) ^ swzr;
                *reinterpret_cast<uint4*>(&sA[r * 64 + (byte >> 1)]) = v;
            }
        }
        // ---- stage B [128 cols][64 k] bf16 ----
        {
            const uint4* g = reinterpret_cast<const uint4*>(self ? Wsbf : Wnbf);
#pragma unroll
            for (int q = 0; q < 4; ++q) {
                uint4 v = g[(r * DIM + kg + hh * 32 + q * 8) >> 3];
                int byte = (hh * 64 + q * 16) ^ swzr;
                *reinterpret_cast<uint4*>(&sB[r * 64 + (byte >> 1)]) = v;
            }
        }
        __syncthreads();
#pragma unroll
        for (int ks = 0; ks < 2; ++ks) {
            short8 a[4], b[4];
#pragma unroll
            for (int fm = 0; fm < 4; ++fm) {
                int rr = wr * 64 + fm * 16 + lr;
                int byte = (ks * 64 + lg * 16) ^ ((rr & 7) << 4);
                a[fm] = *reinterpret_cast<const short8*>(&sA[rr * 64 + (byte >> 1)]);
            }
#pragma unroll
            for (int fn = 0; fn < 4; ++fn) {
                int cc = wc * 64 + fn * 16 + lr;
                int byte = (ks * 64 + lg * 16) ^ ((cc & 7) << 4);
                b[fn] = *reinterpret_cast<const short8*>(&sB[cc * 64 + (byte >> 1)]);
            }
#pragma unroll
            for (int fm = 0; fm < 4; ++fm)
#pragma unroll
                for (int fn = 0; fn < 4; ++fn)
                    acc[fm][fn] = __builtin_amdgcn_mfma_f32_16x16x32_bf16(
                        a[fm], b[fn], acc[fm][fn], 0, 0, 0);
        }
    }

    float bias[4], wa[4], wb[4];
#pragma unroll
    for (int fn = 0; fn < 4; ++fn) {
        int c = wc * 64 + fn * 16 + lr;
        bias[fn] = bs[c] + bn[c];
        wa[fn] = w2a[c];
        wb[fn] = w2b[c];
    }
#pragma unroll
    for (int fm = 0; fm < 4; ++fm) {
#pragma unroll
        for (int reg = 0; reg < 4; ++reg) {
            float pa = 0.f, pb = 0.f;
#pragma unroll
            for (int fn = 0; fn < 4; ++fn) {
                float h = fmaxf(acc[fm][fn][reg] + bias[fn], 0.f);
                pa = fmaf(h, wa[fn], pa);
                pb = fmaf(h, wb[fn], pb);
            }
#pragma unroll
            for (int m = 1; m < 16; m <<= 1) {
                pa += __shfl_xor(pa, m);
                pb += __shfl_xor(pb, m);
            }
            if (lr == 0) {
                int rloc = wr * 64 + fm * 16 + lg * 4 + reg;
                pS[wc][0][rloc] = pa;
                pS[wc][1][rloc] = pb;
            }
        }
    }
    __syncthreads();
    if (tid < 128) {
        int go = row0 + tid;
        if (go < N_NODES) {
            dself[go] = pS[0][0][tid] + pS[1][0][tid];
            dcross[go] = pS[0][1][tid] + pS[1][1][tid];
        }
    }
}

__global__ __launch_bounds__(256) void finalize_kernel(
    const float* __restrict__ dself_u, const float* __restrict__ smean_u,
    const float* __restrict__ b2bs, const float* __restrict__ b2bn,
    const float* __restrict__ dself_t, const float* __restrict__ smean_t,
    const float* __restrict__ b2ps, const float* __restrict__ b2pn,
    float* __restrict__ out) {
    int i = blockIdx.x * 256 + threadIdx.x;
    if (i >= N_NODES) return;
    out[i] = dself_u[i] + smean_u[i] + b2bs[0] + b2bn[0];
    out[N_NODES + i] = dself_t[i] + smean_t[i] + b2ps[0] + b2pn[0];
}

extern "C" void kernel_launch(void* const* d_in, const int* in_sizes, int n_in,
                              void* d_out, int out_size, void* d_ws, size_t ws_size,
                              hipStream_t stream) {
    const float* x_user  = (const float*)d_in[0];
    const float* x_tweet = (const float*)d_in[1];
    const float* w1ps = (const float*)d_in[2];  const float* b1ps = (const float*)d_in[3];
    const float* w1pn = (const float*)d_in[4];  const float* b1pn = (const float*)d_in[5];
    const float* w1bs = (const float*)d_in[6];  const float* b1bs = (const float*)d_in[7];
    const float* w1bn = (const float*)d_in[8];  const float* b1bn = (const float*)d_in[9];
    const float* w2ps = (const float*)d_in[10]; const float* b2ps = (const float*)d_in[11];
    const float* w2pn = (const float*)d_in[12]; const float* b2pn = (const float*)d_in[13];
    const float* w2bs = (const float*)d_in[14]; const float* b2bs = (const float*)d_in[15];
    const float* w2bn = (const float*)d_in[16]; const float* b2bn = (const float*)d_in[17];
    const int* src_posts = (const int*)d_in[18];
    const int* dst_posts = (const int*)d_in[19];
    const int* src_pb    = (const int*)d_in[20];
    const int* dst_pb    = (const int*)d_in[21];
    float* out = (float*)d_out;

    // ---- workspace layout (16B aligned regions) ----
    char* wsb = (char*)d_ws;
    ushort* nbf     = (ushort*)wsb;   wsb += (size_t)N_NODES * DIM * 2;      // 25.6 MB
    int* head2      = (int*)wsb;      wsb += (size_t)2 * N_NODES * 4;        //  0.8 MB
    int2* entry2    = (int2*)wsb;     wsb += (size_t)2 * N_EDGES * 8;        //  8.0 MB
    ushort* wbf_ps  = (ushort*)wsb;   wsb += (size_t)DIM * DIM * 2;
    ushort* wbf_pn  = (ushort*)wsb;   wsb += (size_t)DIM * DIM * 2;
    ushort* wbf_bs  = (ushort*)wsb;   wsb += (size_t)DIM * DIM * 2;
    ushort* wbf_bn  = (ushort*)wsb;   wsb += (size_t)DIM * DIM * 2;
    float* dself_t  = (float*)wsb;    wsb += (size_t)N_NODES * 4;
    float* scross_t = (float*)wsb;    wsb += (size_t)N_NODES * 4;
    float* dself_u  = (float*)wsb;    wsb += (size_t)N_NODES * 4;
    float* scross_u = (float*)wsb;    wsb += (size_t)N_NODES * 4;
    float* smean_t  = (float*)wsb;    wsb += (size_t)N_NODES * 4;
    float* smean_u  = (float*)wsb;    wsb += (size_t)N_NODES * 4;
    // bf16 feature copies last, so the fallback path's footprint is unchanged
    ushort* xbf_u   = (ushort*)wsb;   wsb += (size_t)N_NODES * DIM * 2;      // 25.6 MB
    ushort* xbf_t   = (ushort*)wsb;   wsb += (size_t)N_NODES * DIM * 2;      // 25.6 MB
    const bool use_bf = ((size_t)(wsb - (char*)d_ws) <= ws_size);

    const int* head_posts = head2;
    const int* head_pb    = head2 + N_NODES;
    const int2* ent_posts = entry2;
    const int2* ent_pb    = entry2 + N_EDGES;

    const int gE = (N_EDGES + 255) / 256;
    const int gN = (N_NODES + 255) / 256;
    const int gG = (N_NODES + 127) / 128;   // 782

    // ---- dtype conversions ----
    cvtw_kernel<<<dim3(16, 4), 256, 0, stream>>>(w1ps, w1pn, w1bs, w1bn,
                                                 wbf_ps, wbf_pn, wbf_bs, wbf_bn);
    if (use_bf)
        cvtx_kernel<<<dim3(12500, 2), 256, 0, stream>>>(x_user, x_tweet, xbf_u, xbf_t);

    // ---- build both adjacency lists (one pass, coalesced entry writes) ----
    hipMemsetAsync(head2, 0xFF, 2 * N_NODES * sizeof(int), stream);   // -1 sentinels
    build_lists2_kernel<<<dim3(gE, 2), 256, 0, stream>>>(src_posts, dst_posts,
                                                         src_pb, dst_pb, head2, entry2);

    // ---- relation 'posts': tweet side ----
    if (use_bf)
        seg_mean_bf16_list_kernel<<<(N_NODES * 16 + 255) / 256, 256, 0, stream>>>(
            xbf_u, head_posts, ent_posts, nbf);
    else
        seg_mean_f32_list_kernel<<<(N_NODES * 32 + 255) / 256, 256, 0, stream>>>(
            x_user, head_posts, ent_posts, nbf);
    gemm_mfma_kernel<<<gG, 256, 0, stream>>>(x_tweet, nbf, wbf_ps, wbf_pn,
                                             b1ps, b1pn, w2ps, w2bn, dself_t, scross_t);

    // ---- relation 'posted_by': user side ----
    if (use_bf)
        seg_mean_bf16_list_kernel<<<(N_NODES * 16 + 255) / 256, 256, 0, stream>>>(
            xbf_t, head_pb, ent_pb, nbf);
    else
        seg_mean_f32_list_kernel<<<(N_NODES * 32 + 255) / 256, 256, 0, stream>>>(
            x_tweet, head_pb, ent_pb, nbf);
    gemm_mfma_kernel<<<gG, 256, 0, stream>>>(x_user, nbf, wbf_bs, wbf_bn,
                                             b1bs, b1bn, w2bs, w2pn, dself_u, scross_u);

    // ---- layer-2 neighbor terms (scalar seg means over same lists, batched) ----
    scalar_seg2_list_kernel<<<dim3(gN, 2), 256, 0, stream>>>(scross_u, scross_t,
                                                             head2, entry2,
                                                             smean_t, smean_u);

    finalize_kernel<<<gN, 256, 0, stream>>>(dself_u, smean_u, b2bs, b2bn,
                                            dself_t, smean_t, b2ps, b2pn, out);
}

// Round 6
// 211.394 us; speedup vs baseline: 9.6689x; 1.0552x over previous
//
#include <hip/hip_runtime.h>

#define N_NODES 100000
#define N_EDGES 500000
#define DIM 128
#define HSTR 4   // head entry stride in ints (16B) — reduces atomic line conflicts

typedef __attribute__((ext_vector_type(8))) short short8;   // 8 bf16 = 4 VGPRs
typedef __attribute__((ext_vector_type(4))) float f32x4;

__device__ __forceinline__ ushort f2bf(float f) {
    unsigned u = __float_as_uint(f);
    u += 0x7FFF + ((u >> 16) & 1);   // round-to-nearest-even
    return (ushort)(u >> 16);
}
__device__ __forceinline__ float bf2f(ushort s) {
    return __uint_as_float(((unsigned)s) << 16);
}

// ---------------- per-node linked-list build ----------------
// head[d*HSTR] = last edge id with dst d; entry[e] = {src[e], prev}. One pass:
// atomicExch on padded L2-resident head + fully coalesced 8B entry writes.

__global__ __launch_bounds__(256) void build_lists2_kernel(
    const int* __restrict__ s0, const int* __restrict__ d0,
    const int* __restrict__ s1, const int* __restrict__ d1,
    int* __restrict__ head2, int2* __restrict__ entry2) {
    const int rel = blockIdx.y;
    const int* src = rel ? s1 : s0;
    const int* dst = rel ? d1 : d0;
    int* head = head2 + (size_t)rel * N_NODES * HSTR;
    int2* entry = entry2 + (size_t)rel * N_EDGES;
    int e = blockIdx.x * 256 + threadIdx.x;
    if (e < N_EDGES) {
        int d = dst[e];
        int old = atomicExch(&head[(size_t)d * HSTR], e);
        entry[e] = make_int2(src[e], old);
    }
}

// ---------------- dtype conversions ----------------

__global__ __launch_bounds__(256) void cvtw_kernel(
    const float* __restrict__ w0, const float* __restrict__ w1,
    const float* __restrict__ w2, const float* __restrict__ w3,
    ushort* __restrict__ o0, ushort* __restrict__ o1,
    ushort* __restrict__ o2, ushort* __restrict__ o3) {
    int a = blockIdx.y;
    const float* in = (a == 0) ? w0 : (a == 1) ? w1 : (a == 2) ? w2 : w3;
    ushort* out = (a == 0) ? o0 : (a == 1) ? o1 : (a == 2) ? o2 : o3;
    int i = (blockIdx.x * 256 + threadIdx.x) * 4;
    float4 v = *reinterpret_cast<const float4*>(&in[i]);
    ushort4 u = make_ushort4(f2bf(v.x), f2bf(v.y), f2bf(v.z), f2bf(v.w));
    *reinterpret_cast<ushort4*>(&out[i]) = u;
}

__global__ __launch_bounds__(256) void cvtx_kernel(const float* __restrict__ x0,
                                                   const float* __restrict__ x1,
                                                   ushort* __restrict__ o0,
                                                   ushort* __restrict__ o1) {
    const float* in = blockIdx.y ? x1 : x0;
    ushort* out = blockIdx.y ? o1 : o0;
    int i = (blockIdx.x * 256 + threadIdx.x) * 4;
    float4 v = *reinterpret_cast<const float4*>(&in[i]);
    ushort4 u = make_ushort4(f2bf(v.x), f2bf(v.y), f2bf(v.z), f2bf(v.w));
    *reinterpret_cast<ushort4*>(&out[i]) = u;
}

// ---------------- segment means via list traversal ----------------

// bf16 gather: 16 lanes per node, each lane owns 8 contiguous feats (16B loads).
__global__ __launch_bounds__(256) void seg_mean_bf16_list_kernel(
    const ushort* __restrict__ x, const int* __restrict__ head,
    const int2* __restrict__ entry, ushort* __restrict__ outbf) {
    int idx = blockIdx.x * 256 + threadIdx.x;
    int node = idx >> 4;
    if (node >= N_NODES) return;
    int f = (idx & 15) << 3;
    float acc[8];
#pragma unroll
    for (int j = 0; j < 8; ++j) acc[j] = 0.f;
    int cnt = 0;
    int e = head[(size_t)node * HSTR];
    while (e >= 0) {
        int2 nd = entry[e];   // one dependent 8B load per hop (broadcast in group)
        ++cnt;
        short8 v = *reinterpret_cast<const short8*>(&x[(size_t)nd.x * DIM + f]);
#pragma unroll
        for (int j = 0; j < 8; ++j) acc[j] += bf2f((ushort)v[j]);
        e = nd.y;
    }
    float r = 1.0f / fmaxf((float)cnt, 1.0f);
    union { ushort s[8]; uint4 v; } u;
#pragma unroll
    for (int j = 0; j < 8; ++j) u.s[j] = f2bf(acc[j] * r);
    *reinterpret_cast<uint4*>(&outbf[(size_t)node * DIM + f]) = u.v;
}

// f32 fallback (workspace too small for bf16 feature copies): 32 lanes/node.
__global__ __launch_bounds__(256) void seg_mean_f32_list_kernel(
    const float* __restrict__ x, const int* __restrict__ head,
    const int2* __restrict__ entry, ushort* __restrict__ outbf) {
    int idx = blockIdx.x * 256 + threadIdx.x;
    int node = idx >> 5;
    if (node >= N_NODES) return;
    int f = (idx & 31) << 2;
    float4 acc = make_float4(0.f, 0.f, 0.f, 0.f);
    int cnt = 0;
    int e = head[(size_t)node * HSTR];
    while (e >= 0) {
        int2 nd = entry[e];
        ++cnt;
        float4 v = *reinterpret_cast<const float4*>(&x[(size_t)nd.x * DIM + f]);
        acc.x += v.x; acc.y += v.y; acc.z += v.z; acc.w += v.w;
        e = nd.y;
    }
    float r = 1.0f / fmaxf((float)cnt, 1.0f);
    ushort4 u = make_ushort4(f2bf(acc.x * r), f2bf(acc.y * r),
                             f2bf(acc.z * r), f2bf(acc.w * r));
    *reinterpret_cast<ushort4*>(&outbf[node * DIM + f]) = u;
}

// ---------------- fused layer-1 MFMA GEMM + layer-2 dots (bf16 A) ----------------
// h = relu(Xs@Ws.T + bs + Nm@Wn.T + bn); epilogue: dself=h·w2a, dcross=h·w2b.
// 128x128 tile, 4 waves (2x2 of 64x64), K=256 (self 0..127, neigh 128..255), BK=64.
// LDS tiles [row][64] bf16, XOR-swizzled: byte_in_row ^= (row&7)<<4.
__global__ __launch_bounds__(256) void gemm_mfma_bf_kernel(
    const ushort* __restrict__ Xsbf,   // [N][128] bf16 self features
    const ushort* __restrict__ Nm,     // [N][128] bf16 neighbor means
    const ushort* __restrict__ Wsbf,   // [128][128] bf16 (row-major [out][in])
    const ushort* __restrict__ Wnbf,
    const float* __restrict__ bs, const float* __restrict__ bn,
    const float* __restrict__ w2a, const float* __restrict__ w2b,
    float* __restrict__ dself, float* __restrict__ dcross) {
    __shared__ ushort sA[128 * 64];
    __shared__ ushort sB[128 * 64];
    __shared__ float pS[2][2][128];   // [wc][pa/pb][row]

    const int tid = threadIdx.x;
    const int lane = tid & 63;
    const int wid = tid >> 6;
    const int wr = wid >> 1, wc = wid & 1;
    const int lr = lane & 15, lg = lane >> 4;
    const int row0 = blockIdx.x * 128;

    f32x4 acc[4][4];
#pragma unroll
    for (int i = 0; i < 4; ++i)
#pragma unroll
        for (int j = 0; j < 4; ++j) acc[i][j] = (f32x4){0.f, 0.f, 0.f, 0.f};

    const int r = tid >> 1;
    const int hh = tid & 1;
    const int grow = row0 + r;
    const int swzr = (r & 7) << 4;

    for (int kb = 0; kb < 256; kb += 64) {
        const int kg = kb & 127;
        const bool self = (kb < 128);
        __syncthreads();
        // ---- stage A [128 rows][64 k] bf16 (uniform uint4 copies) ----
        {
            const uint4* g = reinterpret_cast<const uint4*>(self ? Xsbf : Nm);
#pragma unroll
            for (int q = 0; q < 4; ++q) {
                uint4 v = make_uint4(0, 0, 0, 0);
                if (grow < N_NODES)
                    v = g[((size_t)grow * DIM + kg + hh * 32 + q * 8) >> 3];
                int byte = (hh * 64 + q * 16) ^ swzr;
                *reinterpret_cast<uint4*>(&sA[r * 64 + (byte >> 1)]) = v;
            }
        }
        // ---- stage B [128 cols][64 k] bf16 ----
        {
            const uint4* g = reinterpret_cast<const uint4*>(self ? Wsbf : Wnbf);
#pragma unroll
            for (int q = 0; q < 4; ++q) {
                uint4 v = g[(r * DIM + kg + hh * 32 + q * 8) >> 3];
                int byte = (hh * 64 + q * 16) ^ swzr;
                *reinterpret_cast<uint4*>(&sB[r * 64 + (byte >> 1)]) = v;
            }
        }
        __syncthreads();
#pragma unroll
        for (int ks = 0; ks < 2; ++ks) {
            short8 a[4], b[4];
#pragma unroll
            for (int fm = 0; fm < 4; ++fm) {
                int rr = wr * 64 + fm * 16 + lr;
                int byte = (ks * 64 + lg * 16) ^ ((rr & 7) << 4);
                a[fm] = *reinterpret_cast<const short8*>(&sA[rr * 64 + (byte >> 1)]);
            }
#pragma unroll
            for (int fn = 0; fn < 4; ++fn) {
                int cc = wc * 64 + fn * 16 + lr;
                int byte = (ks * 64 + lg * 16) ^ ((cc & 7) << 4);
                b[fn] = *reinterpret_cast<const short8*>(&sB[cc * 64 + (byte >> 1)]);
            }
#pragma unroll
            for (int fm = 0; fm < 4; ++fm)
#pragma unroll
                for (int fn = 0; fn < 4; ++fn)
                    acc[fm][fn] = __builtin_amdgcn_mfma_f32_16x16x32_bf16(
                        a[fm], b[fn], acc[fm][fn], 0, 0, 0);
        }
    }

    float bias[4], wa[4], wb[4];
#pragma unroll
    for (int fn = 0; fn < 4; ++fn) {
        int c = wc * 64 + fn * 16 + lr;
        bias[fn] = bs[c] + bn[c];
        wa[fn] = w2a[c];
        wb[fn] = w2b[c];
    }
#pragma unroll
    for (int fm = 0; fm < 4; ++fm) {
#pragma unroll
        for (int reg = 0; reg < 4; ++reg) {
            float pa = 0.f, pb = 0.f;
#pragma unroll
            for (int fn = 0; fn < 4; ++fn) {
                float h = fmaxf(acc[fm][fn][reg] + bias[fn], 0.f);
                pa = fmaf(h, wa[fn], pa);
                pb = fmaf(h, wb[fn], pb);
            }
#pragma unroll
            for (int m = 1; m < 16; m <<= 1) {
                pa += __shfl_xor(pa, m);
                pb += __shfl_xor(pb, m);
            }
            if (lr == 0) {
                int rloc = wr * 64 + fm * 16 + lg * 4 + reg;
                pS[wc][0][rloc] = pa;
                pS[wc][1][rloc] = pb;
            }
        }
    }
    __syncthreads();
    if (tid < 128) {
        int go = row0 + tid;
        if (go < N_NODES) {
            dself[go] = pS[0][0][tid] + pS[1][0][tid];
            dcross[go] = pS[0][1][tid] + pS[1][1][tid];
        }
    }
}

// f32-A fallback GEMM (only used when ws too small for bf16 feature copies)
__global__ __launch_bounds__(256) void gemm_mfma_kernel(
    const float* __restrict__ Xs, const ushort* __restrict__ Nm,
    const ushort* __restrict__ Wsbf, const ushort* __restrict__ Wnbf,
    const float* __restrict__ bs, const float* __restrict__ bn,
    const float* __restrict__ w2a, const float* __restrict__ w2b,
    float* __restrict__ dself, float* __restrict__ dcross) {
    __shared__ ushort sA[128 * 64];
    __shared__ ushort sB[128 * 64];
    __shared__ float pS[2][2][128];

    const int tid = threadIdx.x;
    const int lane = tid & 63;
    const int wid = tid >> 6;
    const int wr = wid >> 1, wc = wid & 1;
    const int lr = lane & 15, lg = lane >> 4;
    const int row0 = blockIdx.x * 128;

    f32x4 acc[4][4];
#pragma unroll
    for (int i = 0; i < 4; ++i)
#pragma unroll
        for (int j = 0; j < 4; ++j) acc[i][j] = (f32x4){0.f, 0.f, 0.f, 0.f};

    const int r = tid >> 1;
    const int hh = tid & 1;
    const int grow = row0 + r;
    const int swzr = (r & 7) << 4;

    for (int kb = 0; kb < 256; kb += 64) {
        const int kg = kb & 127;
        const bool self = (kb < 128);
        __syncthreads();
        if (self) {
            const float4* g = reinterpret_cast<const float4*>(Xs);
#pragma unroll
            for (int q = 0; q < 4; ++q) {
                float4 v0 = make_float4(0.f, 0.f, 0.f, 0.f), v1 = v0;
                if (grow < N_NODES) {
                    size_t bi = ((size_t)grow * DIM + kg + hh * 32 + q * 8) >> 2;
                    v0 = g[bi];
                    v1 = g[bi + 1];
                }
                union { ushort s[8]; uint4 v; } u;
                u.s[0] = f2bf(v0.x); u.s[1] = f2bf(v0.y);
                u.s[2] = f2bf(v0.z); u.s[3] = f2bf(v0.w);
                u.s[4] = f2bf(v1.x); u.s[5] = f2bf(v1.y);
                u.s[6] = f2bf(v1.z); u.s[7] = f2bf(v1.w);
                int byte = (hh * 64 + q * 16) ^ swzr;
                *reinterpret_cast<uint4*>(&sA[r * 64 + (byte >> 1)]) = u.v;
            }
        } else {
            const uint4* g = reinterpret_cast<const uint4*>(Nm);
#pragma unroll
            for (int q = 0; q < 4; ++q) {
                uint4 v = make_uint4(0, 0, 0, 0);
                if (grow < N_NODES)
                    v = g[((size_t)grow * DIM + kg + hh * 32 + q * 8) >> 3];
                int byte = (hh * 64 + q * 16) ^ swzr;
                *reinterpret_cast<uint4*>(&sA[r * 64 + (byte >> 1)]) = v;
            }
        }
        {
            const uint4* g = reinterpret_cast<const uint4*>(self ? Wsbf : Wnbf);
#pragma unroll
            for (int q = 0; q < 4; ++q) {
                uint4 v = g[(r * DIM + kg + hh * 32 + q * 8) >> 3];
                int byte = (hh * 64 + q * 16) ^ swzr;
                *reinterpret_cast<uint4*>(&sB[r * 64 + (byte >> 1)]) = v;
            }
        }
        __syncthreads();
#pragma unroll
        for (int ks = 0; ks < 2; ++ks) {
            short8 a[4], b[4];
#pragma unroll
            for (int fm = 0; fm < 4; ++fm) {
                int rr = wr * 64 + fm * 16 + lr;
                int byte = (ks * 64 + lg * 16) ^ ((rr & 7) << 4);
                a[fm] = *reinterpret_cast<const short8*>(&sA[rr * 64 + (byte >> 1)]);
            }
#pragma unroll
            for (int fn = 0; fn < 4; ++fn) {
                int cc = wc * 64 + fn * 16 + lr;
                int byte = (ks * 64 + lg * 16) ^ ((cc & 7) << 4);
                b[fn] = *reinterpret_cast<const short8*>(&sB[cc * 64 + (byte >> 1)]);
            }
#pragma unroll
            for (int fm = 0; fm < 4; ++fm)
#pragma unroll
                for (int fn = 0; fn < 4; ++fn)
                    acc[fm][fn] = __builtin_amdgcn_mfma_f32_16x16x32_bf16(
                        a[fm], b[fn], acc[fm][fn], 0, 0, 0);
        }
    }

    float bias[4], wa[4], wb[4];
#pragma unroll
    for (int fn = 0; fn < 4; ++fn) {
        int c = wc * 64 + fn * 16 + lr;
        bias[fn] = bs[c] + bn[c];
        wa[fn] = w2a[c];
        wb[fn] = w2b[c];
    }
#pragma unroll
    for (int fm = 0; fm < 4; ++fm) {
#pragma unroll
        for (int reg = 0; reg < 4; ++reg) {
            float pa = 0.f, pb = 0.f;
#pragma unroll
            for (int fn = 0; fn < 4; ++fn) {
                float h = fmaxf(acc[fm][fn][reg] + bias[fn], 0.f);
                pa = fmaf(h, wa[fn], pa);
                pb = fmaf(h, wb[fn], pb);
            }
#pragma unroll
            for (int m = 1; m < 16; m <<= 1) {
                pa += __shfl_xor(pa, m);
                pb += __shfl_xor(pb, m);
            }
            if (lr == 0) {
                int rloc = wr * 64 + fm * 16 + lg * 4 + reg;
                pS[wc][0][rloc] = pa;
                pS[wc][1][rloc] = pb;
            }
        }
    }
    __syncthreads();
    if (tid < 128) {
        int go = row0 + tid;
        if (go < N_NODES) {
            dself[go] = pS[0][0][tid] + pS[1][0][tid];
            dcross[go] = pS[0][1][tid] + pS[1][1][tid];
        }
    }
}

// ---------------- fused layer-2 scalar seg-means + output ----------------
// out_user[i]  = dself_u[i] + mean_{e in pb(i)} scross_t[src] + b2bs + b2bn
// out_tweet[i] = dself_t[i] + mean_{e in posts(i)} scross_u[src] + b2ps + b2pn
__global__ __launch_bounds__(256) void scalar_finalize_kernel(
    const float* __restrict__ dself_u, const float* __restrict__ dself_t,
    const float* __restrict__ scross_u, const float* __restrict__ scross_t,
    const int* __restrict__ head2, const int2* __restrict__ entry2,
    const float* __restrict__ b2bs, const float* __restrict__ b2bn,
    const float* __restrict__ b2ps, const float* __restrict__ b2pn,
    float* __restrict__ out) {
    int i = blockIdx.x * 256 + threadIdx.x;
    if (i >= N_NODES) return;
    // tweet side: relation 'posts' (rel 0), messages from users (scross_u)
    {
        float a = 0.f; int cnt = 0;
        int e = head2[(size_t)i * HSTR];
        while (e >= 0) {
            int2 nd = entry2[e];
            ++cnt;
            a += scross_u[nd.x];
            e = nd.y;
        }
        out[N_NODES + i] = dself_t[i] + a / fmaxf((float)cnt, 1.0f) + b2ps[0] + b2pn[0];
    }
    // user side: relation 'posted_by' (rel 1), messages from tweets (scross_t)
    {
        float a = 0.f; int cnt = 0;
        int e = head2[((size_t)N_NODES + i) * HSTR];
        while (e >= 0) {
            int2 nd = entry2[(size_t)N_EDGES + e];
            ++cnt;
            a += scross_t[nd.x];
            e = nd.y;
        }
        out[i] = dself_u[i] + a / fmaxf((float)cnt, 1.0f) + b2bs[0] + b2bn[0];
    }
}

extern "C" void kernel_launch(void* const* d_in, const int* in_sizes, int n_in,
                              void* d_out, int out_size, void* d_ws, size_t ws_size,
                              hipStream_t stream) {
    const float* x_user  = (const float*)d_in[0];
    const float* x_tweet = (const float*)d_in[1];
    const float* w1ps = (const float*)d_in[2];  const float* b1ps = (const float*)d_in[3];
    const float* w1pn = (const float*)d_in[4];  const float* b1pn = (const float*)d_in[5];
    const float* w1bs = (const float*)d_in[6];  const float* b1bs = (const float*)d_in[7];
    const float* w1bn = (const float*)d_in[8];  const float* b1bn = (const float*)d_in[9];
    const float* w2ps = (const float*)d_in[10]; const float* b2ps = (const float*)d_in[11];
    const float* w2pn = (const float*)d_in[12]; const float* b2pn = (const float*)d_in[13];
    const float* w2bs = (const float*)d_in[14]; const float* b2bs = (const float*)d_in[15];
    const float* w2bn = (const float*)d_in[16]; const float* b2bn = (const float*)d_in[17];
    const int* src_posts = (const int*)d_in[18];
    const int* dst_posts = (const int*)d_in[19];
    const int* src_pb    = (const int*)d_in[20];
    const int* dst_pb    = (const int*)d_in[21];
    float* out = (float*)d_out;

    // ---- workspace layout (16B aligned regions) ----
    char* wsb = (char*)d_ws;
    ushort* nbf     = (ushort*)wsb;   wsb += (size_t)N_NODES * DIM * 2;          // 25.6 MB
    int* head2      = (int*)wsb;      wsb += (size_t)2 * N_NODES * HSTR * 4;     //  3.2 MB
    int2* entry2    = (int2*)wsb;     wsb += (size_t)2 * N_EDGES * 8;            //  8.0 MB
    ushort* wbf_ps  = (ushort*)wsb;   wsb += (size_t)DIM * DIM * 2;
    ushort* wbf_pn  = (ushort*)wsb;   wsb += (size_t)DIM * DIM * 2;
    ushort* wbf_bs  = (ushort*)wsb;   wsb += (size_t)DIM * DIM * 2;
    ushort* wbf_bn  = (ushort*)wsb;   wsb += (size_t)DIM * DIM * 2;
    float* dself_t  = (float*)wsb;    wsb += (size_t)N_NODES * 4;
    float* scross_t = (float*)wsb;    wsb += (size_t)N_NODES * 4;
    float* dself_u  = (float*)wsb;    wsb += (size_t)N_NODES * 4;
    float* scross_u = (float*)wsb;    wsb += (size_t)N_NODES * 4;
    // bf16 feature copies last, so the fallback path's footprint is unchanged
    ushort* xbf_u   = (ushort*)wsb;   wsb += (size_t)N_NODES * DIM * 2;          // 25.6 MB
    ushort* xbf_t   = (ushort*)wsb;   wsb += (size_t)N_NODES * DIM * 2;          // 25.6 MB
    const bool use_bf = ((size_t)(wsb - (char*)d_ws) <= ws_size);

    const int* head_posts = head2;
    const int* head_pb    = head2 + (size_t)N_NODES * HSTR;
    const int2* ent_posts = entry2;
    const int2* ent_pb    = entry2 + N_EDGES;

    const int gE = (N_EDGES + 255) / 256;
    const int gN = (N_NODES + 255) / 256;
    const int gG = (N_NODES + 127) / 128;   // 782

    // ---- dtype conversions ----
    cvtw_kernel<<<dim3(16, 4), 256, 0, stream>>>(w1ps, w1pn, w1bs, w1bn,
                                                 wbf_ps, wbf_pn, wbf_bs, wbf_bn);
    if (use_bf)
        cvtx_kernel<<<dim3(12500, 2), 256, 0, stream>>>(x_user, x_tweet, xbf_u, xbf_t);

    // ---- build both adjacency lists (one pass, coalesced entry writes) ----
    hipMemsetAsync(head2, 0xFF, (size_t)2 * N_NODES * HSTR * sizeof(int), stream);
    build_lists2_kernel<<<dim3(gE, 2), 256, 0, stream>>>(src_posts, dst_posts,
                                                         src_pb, dst_pb, head2, entry2);

    // ---- relation 'posts': tweet side ----
    if (use_bf) {
        seg_mean_bf16_list_kernel<<<(N_NODES * 16 + 255) / 256, 256, 0, stream>>>(
            xbf_u, head_posts, ent_posts, nbf);
        gemm_mfma_bf_kernel<<<gG, 256, 0, stream>>>(xbf_t, nbf, wbf_ps, wbf_pn,
                                                    b1ps, b1pn, w2ps, w2bn,
                                                    dself_t, scross_t);
    } else {
        seg_mean_f32_list_kernel<<<(N_NODES * 32 + 255) / 256, 256, 0, stream>>>(
            x_user, head_posts, ent_posts, nbf);
        gemm_mfma_kernel<<<gG, 256, 0, stream>>>(x_tweet, nbf, wbf_ps, wbf_pn,
                                                 b1ps, b1pn, w2ps, w2bn,
                                                 dself_t, scross_t);
    }

    // ---- relation 'posted_by': user side ----
    if (use_bf) {
        seg_mean_bf16_list_kernel<<<(N_NODES * 16 + 255) / 256, 256, 0, stream>>>(
            xbf_t, head_pb, ent_pb, nbf);
        gemm_mfma_bf_kernel<<<gG, 256, 0, stream>>>(xbf_u, nbf, wbf_bs, wbf_bn,
                                                    b1bs, b1bn, w2bs, w2pn,
                                                    dself_u, scross_u);
    } else {
        seg_mean_f32_list_kernel<<<(N_NODES * 32 + 255) / 256, 256, 0, stream>>>(
            x_tweet, head_pb, ent_pb, nbf);
        gemm_mfma_kernel<<<gG, 256, 0, stream>>>(x_user, nbf, wbf_bs, wbf_bn,
                                                 b1bs, b1bn, w2bs, w2pn,
                                                 dself_u, scross_u);
    }

    // ---- fused layer-2 scalar seg-means + output write ----
    scalar_finalize_kernel<<<gN, 256, 0, stream>>>(dself_u, dself_t, scross_u, scross_t,
                                                   head2, entry2, b2bs, b2bn, b2ps, b2pn,
                                                   out);
}